// Round 3
// baseline (1602.683 us; speedup 1.0000x reference)
//
#include <hip/hip_runtime.h>
#include <stdint.h>

#define D_MODEL 1024
#define D_STATE 16
#define D_INNER 2048
#define BATCH   4
#define SEQ     2048
#define ML      (BATCH*SEQ)   // 8192 rows

typedef unsigned short u16;
typedef u16   u16x8  __attribute__((ext_vector_type(8)));
typedef short s16x8  __attribute__((ext_vector_type(8)));
typedef float f32x4  __attribute__((ext_vector_type(4)));

__device__ __forceinline__ float b2f(u16 u){
  union { uint32_t i; float f; } v; v.i = ((uint32_t)u) << 16; return v.f;
}
__device__ __forceinline__ u16 f2b(float f){
  uint32_t x = __float_as_uint(f);
  return (u16)((x + 0x7fffu + ((x >> 16) & 1u)) >> 16);   // RNE
}
__device__ __forceinline__ float silu_f(float v){
  return v / (1.f + __expf(-v));
}

// ------------- transpose + cast: in f32 (R x C) -> out bf16 (C x R) -------------
__global__ __launch_bounds__(256) void transpose_cast_k(const float* __restrict__ in,
                                                        u16* __restrict__ out,
                                                        int R, int C){
  __shared__ float tile[32][33];
  int bx = blockIdx.x * 32, by = blockIdx.y * 32;
  int tx = threadIdx.x & 31, ty = threadIdx.x >> 5;   // ty in 0..7
  #pragma unroll
  for (int i = 0; i < 32; i += 8)
    tile[ty + i][tx] = in[(size_t)(by + ty + i) * C + bx + tx];
  __syncthreads();
  #pragma unroll
  for (int i = 0; i < 32; i += 8)
    out[(size_t)(bx + ty + i) * R + by + tx] = f2b(tile[tx][ty + i]);
}

// ------------- MFMA GEMM: D = A(MxK) * Bt(NxK)^T (+bias, epilogue) -------------
// AF32: A source is f32 (converted to bf16 during LDS staging); else bf16.
// MODE 0: outf[row*N+col] = f32(acc + bias[col])          (final output, f32)
// MODE 1: s = silu(acc + bias[col]); col<N/2 -> out0 bf16 (x_ssm), else out1 bf16 (gate)
template<int MODE, int AF32>
__global__ __launch_bounds__(256) void gemm_bt(const void* __restrict__ Av,
                                               const u16* __restrict__ Bt,
                                               const float* __restrict__ bias,
                                               u16* __restrict__ out0,
                                               u16* __restrict__ out1,
                                               float* __restrict__ outf,
                                               int M, int N, int K){
  __shared__ __align__(16) u16 Asb[128*40];   // 128 rows x 32 k, pad to 40
  __shared__ __align__(16) u16 Bsb[128*40];
  const int t    = threadIdx.x;
  const int n0   = blockIdx.x * 128;
  const int m0   = blockIdx.y * 128;
  const int wave = t >> 6, lane = t & 63;
  const int wm   = (wave >> 1) * 64, wn = (wave & 1) * 64;
  const int lrow = lane & 15, kq = (lane >> 4) * 8;

  f32x4 acc[4][4];
  #pragma unroll
  for (int i = 0; i < 4; ++i)
    #pragma unroll
    for (int j = 0; j < 4; ++j)
      acc[i][j] = (f32x4){0.f, 0.f, 0.f, 0.f};

  for (int k0 = 0; k0 < K; k0 += 32) {
    if (AF32) {
      const float* A = (const float*)Av;
      int r = t >> 1, c = (t & 1) * 16;       // thread covers 16 consecutive k
      const float* src = A + (size_t)(m0 + r) * K + k0 + c;
      f32x4 v0 = *(const f32x4*)(src);
      f32x4 v1 = *(const f32x4*)(src + 4);
      f32x4 v2 = *(const f32x4*)(src + 8);
      f32x4 v3 = *(const f32x4*)(src + 12);
      u16x8 p0, p1;
      #pragma unroll
      for (int j = 0; j < 4; ++j){
        p0[j]   = f2b(v0[j]); p0[4+j] = f2b(v1[j]);
        p1[j]   = f2b(v2[j]); p1[4+j] = f2b(v3[j]);
      }
      *(u16x8*)&Asb[r*40 + c]     = p0;
      *(u16x8*)&Asb[r*40 + c + 8] = p1;
    } else {
      const u16* A = (const u16*)Av;
      #pragma unroll
      for (int i = 0; i < 2; ++i) {
        int f = (i*256 + t) * 8;
        int r = f >> 5, c = f & 31;
        *(u16x8*)&Asb[r*40 + c] = *(const u16x8*)&A[(size_t)(m0 + r)*K + k0 + c];
      }
    }
    #pragma unroll
    for (int i = 0; i < 2; ++i) {
      int f = (i*256 + t) * 8;
      int r = f >> 5, c = f & 31;
      *(u16x8*)&Bsb[r*40 + c] = *(const u16x8*)&Bt[(size_t)(n0 + r)*K + k0 + c];
    }
    __syncthreads();
    s16x8 af[4], bfr[4];
    #pragma unroll
    for (int i = 0; i < 4; ++i) af[i]  = *(const s16x8*)&Asb[(wm + i*16 + lrow)*40 + kq];
    #pragma unroll
    for (int j = 0; j < 4; ++j) bfr[j] = *(const s16x8*)&Bsb[(wn + j*16 + lrow)*40 + kq];
    #pragma unroll
    for (int i = 0; i < 4; ++i)
      #pragma unroll
      for (int j = 0; j < 4; ++j)
        acc[i][j] = __builtin_amdgcn_mfma_f32_16x16x32_bf16(af[i], bfr[j], acc[i][j], 0, 0, 0);
    __syncthreads();
  }

  const int Nh = N >> 1;
  #pragma unroll
  for (int i = 0; i < 4; ++i) {
    #pragma unroll
    for (int j = 0; j < 4; ++j) {
      int col = n0 + wn + j*16 + lrow;
      float bv = bias[col];
      #pragma unroll
      for (int r = 0; r < 4; ++r) {
        int row = m0 + wm + i*16 + (lane >> 4)*4 + r;   // C/D: col=lane&15, row=quad*4+reg
        float v = acc[i][j][r] + bv;
        if (MODE == 0) {
          outf[(size_t)row * N + col] = v;              // final output: f32
        } else {
          float s = silu_f(v);
          if (col < Nh) out0[(size_t)row * Nh + col]        = f2b(s);
          else          out1[(size_t)row * Nh + (col - Nh)] = f2b(s);
        }
      }
    }
  }
}

// ------------- conv(3, depthwise) + B/C projections -------------
// one block per (b,l); 256 threads x 8 channels
__global__ __launch_bounds__(256) void conv_bc_k(const u16* __restrict__ xs,
    const float* __restrict__ conv_w, const float* __restrict__ conv_b,
    const float* __restrict__ W_B, const float* __restrict__ b_B, const float* __restrict__ B_mod,
    const float* __restrict__ W_C, const float* __restrict__ b_C, const float* __restrict__ C_mod,
    u16* __restrict__ xconv, float* __restrict__ Bbuf, float* __restrict__ Cbuf){
  int bl = blockIdx.x;
  int b = bl >> 11, l = bl & (SEQ-1);
  int t = threadIdx.x;
  int d = t * 8;
  const u16* row0 = xs + (size_t)bl * D_INNER + d;

  float f0[8], fm[8], fp[8];
  { u16x8 v = *(const u16x8*)row0;
    #pragma unroll
    for (int j = 0; j < 8; ++j) f0[j] = b2f(v[j]); }
  if (l > 0) {
    u16x8 v = *(const u16x8*)(row0 - D_INNER);
    #pragma unroll
    for (int j = 0; j < 8; ++j) fm[j] = b2f(v[j]);
  } else {
    #pragma unroll
    for (int j = 0; j < 8; ++j) fm[j] = 0.f;
  }
  if (l < SEQ-1) {
    u16x8 v = *(const u16x8*)(row0 + D_INNER);
    #pragma unroll
    for (int j = 0; j < 8; ++j) fp[j] = b2f(v[j]);
  } else {
    #pragma unroll
    for (int j = 0; j < 8; ++j) fp[j] = 0.f;
  }

  const float* wp = conv_w + (size_t)d * 3;   // 24 contiguous f32
  float wl[24];
  #pragma unroll
  for (int q = 0; q < 6; ++q){
    f32x4 v = *(const f32x4*)(wp + q*4);
    #pragma unroll
    for (int j = 0; j < 4; ++j) wl[q*4 + j] = v[j];
  }
  float cb[8];
  { f32x4 c0 = *(const f32x4*)(conv_b + d), c1 = *(const f32x4*)(conv_b + d + 4);
    #pragma unroll
    for (int j = 0; j < 4; ++j){ cb[j] = c0[j]; cb[4+j] = c1[j]; } }

  float xc[8];
  #pragma unroll
  for (int j = 0; j < 8; ++j)
    xc[j] = wl[3*j]*fm[j] + wl[3*j+1]*f0[j] + wl[3*j+2]*fp[j] + cb[j];

  u16x8 o;
  #pragma unroll
  for (int j = 0; j < 8; ++j) o[j] = f2b(xc[j]);
  *(u16x8*)(xconv + (size_t)bl * D_INNER + d) = o;

  float sB[16], sC[16];
  #pragma unroll
  for (int s = 0; s < 16; ++s){ sB[s]=0.f; sC[s]=0.f; }
  #pragma unroll
  for (int j = 0; j < 8; ++j){
    const float* wb = W_B + (size_t)(d+j)*16;
    const float* wc = W_C + (size_t)(d+j)*16;
    #pragma unroll
    for (int q = 0; q < 4; ++q){
      f32x4 vb = *(const f32x4*)(wb + q*4);
      f32x4 vc = *(const f32x4*)(wc + q*4);
      #pragma unroll
      for (int s = 0; s < 4; ++s){
        sB[q*4+s] += xc[j]*vb[s];
        sC[q*4+s] += xc[j]*vc[s];
      }
    }
  }
  // wave butterfly reduce (64 lanes)
  #pragma unroll
  for (int m = 1; m < 64; m <<= 1){
    #pragma unroll
    for (int s = 0; s < 16; ++s){
      sB[s] += __shfl_xor(sB[s], m, 64);
      sC[s] += __shfl_xor(sC[s], m, 64);
    }
  }
  __shared__ float red[4][32];
  int wave = t >> 6, lane = t & 63;
  if (lane == 0){
    #pragma unroll
    for (int s = 0; s < 16; ++s){ red[wave][s] = sB[s]; red[wave][16+s] = sC[s]; }
  }
  __syncthreads();
  if (t < 16){
    float v = red[0][t]+red[1][t]+red[2][t]+red[3][t] + b_B[t] + B_mod[b*16+t];
    Bbuf[(size_t)bl*16 + t] = v;
  } else if (t < 32){
    int s = t - 16;
    float v = red[0][16+s]+red[1][16+s]+red[2][16+s]+red[3][16+s] + b_C[s] + C_mod[b*16+s];
    Cbuf[(size_t)bl*16 + s] = v;
  }
}

// ------------- sequential scan over L, fused D-skip + gate -------------
// 32 blocks: (b, 256-channel chunk); one lane per channel, 16 states in regs
__global__ __launch_bounds__(256) void scan_k(const u16* __restrict__ xconv,
    const u16* __restrict__ gate, const float* __restrict__ Bbuf, const float* __restrict__ Cbuf,
    const float* __restrict__ A_log, const float* __restrict__ Dp,
    u16* __restrict__ ybuf){
  int blk = blockIdx.x;
  int b = blk >> 3, chunk = blk & 7;
  int d = chunk*256 + threadIdx.x;

  float Abar[16];
  #pragma unroll
  for (int s = 0; s < 16; ++s)
    Abar[s] = __expf(-0.1f * __expf(A_log[d*16 + s]));
  float h[16];
  #pragma unroll
  for (int s = 0; s < 16; ++s) h[s] = 0.f;
  float Dd = Dp[d];

  size_t base = (size_t)b * SEQ * D_INNER + d;
  const float* Br = Bbuf + (size_t)b * SEQ * 16;
  const float* Cr = Cbuf + (size_t)b * SEQ * 16;

  float Bc[16], Cc[16];
  #pragma unroll
  for (int s = 0; s < 16; ++s){ Bc[s] = Br[s]; Cc[s] = Cr[s]; }
  float xn = b2f(xconv[base]);
  float gn = b2f(gate[base]);

  for (int l = 0; l < SEQ; ++l){
    float x = xn, g = gn;
    float Bl[16], Cl[16];
    #pragma unroll
    for (int s = 0; s < 16; ++s){ Bl[s] = Bc[s]; Cl[s] = Cc[s]; }
    if (l < SEQ-1){
      size_t idx = base + (size_t)(l+1)*D_INNER;
      xn = b2f(xconv[idx]); gn = b2f(gate[idx]);
      #pragma unroll
      for (int s = 0; s < 16; ++s){ Bc[s] = Br[(l+1)*16 + s]; Cc[s] = Cr[(l+1)*16 + s]; }
    }
    float ya[4] = {0.f, 0.f, 0.f, 0.f};
    #pragma unroll
    for (int s = 0; s < 16; ++s){
      float hv = Abar[s]*h[s] + x*Bl[s];
      h[s] = hv;
      ya[s & 3] += hv * Cl[s];
    }
    float y = ((ya[0]+ya[1]) + (ya[2]+ya[3]) + Dd*x) * g;
    ybuf[base + (size_t)l*D_INNER] = f2b(y);
  }
}

extern "C" void kernel_launch(void* const* d_in, const int* in_sizes, int n_in,
                              void* d_out, int out_size, void* d_ws, size_t ws_size,
                              hipStream_t stream){
  const float* x      = (const float*)d_in[0];
  const float* B_mod  = (const float*)d_in[1];
  const float* C_mod  = (const float*)d_in[2];
  const float* W_in   = (const float*)d_in[3];
  const float* b_in   = (const float*)d_in[4];
  const float* conv_w = (const float*)d_in[5];
  const float* conv_b = (const float*)d_in[6];
  const float* A_log  = (const float*)d_in[7];
  const float* Dp     = (const float*)d_in[8];
  const float* W_B    = (const float*)d_in[9];
  const float* b_B    = (const float*)d_in[10];
  const float* W_C    = (const float*)d_in[11];
  const float* b_C    = (const float*)d_in[12];
  const float* W_out  = (const float*)d_in[13];
  const float* b_out  = (const float*)d_in[14];
  float* out = (float*)d_out;   // reference output dtype is float32

  char* ws = (char*)d_ws;
  size_t off = 0;
  auto alloc = [&](size_t bytes)->char* {
    char* p = ws + off; off += (bytes + 255) & ~(size_t)255; return p;
  };
  u16* Wt_in  = (u16*)alloc((size_t)(2*D_INNER)*D_MODEL*2); // 4096x1024 bf16
  u16* Wt_out = (u16*)alloc((size_t)D_MODEL*D_INNER*2);     // 1024x2048 bf16
  u16* xs     = (u16*)alloc((size_t)ML*D_INNER*2);          // x_ssm_silu; reused as y
  u16* gatep  = (u16*)alloc((size_t)ML*D_INNER*2);          // silu(x_res)
  u16* xconv  = (u16*)alloc((size_t)ML*D_INNER*2);
  float* Bbuf = (float*)alloc((size_t)ML*D_STATE*4);
  float* Cbuf = (float*)alloc((size_t)ML*D_STATE*4);
  u16* ybuf = xs;  // xs dead after conv_bc_k

  transpose_cast_k<<<dim3((2*D_INNER)/32, D_MODEL/32), 256, 0, stream>>>(W_in, Wt_in, D_MODEL, 2*D_INNER);
  transpose_cast_k<<<dim3(D_MODEL/32, D_INNER/32),     256, 0, stream>>>(W_out, Wt_out, D_INNER, D_MODEL);

  gemm_bt<1,1><<<dim3((2*D_INNER)/128, ML/128), 256, 0, stream>>>(
      (const void*)x, Wt_in, b_in, xs, gatep, nullptr, ML, 2*D_INNER, D_MODEL);

  conv_bc_k<<<dim3(ML), 256, 0, stream>>>(
      xs, conv_w, conv_b, W_B, b_B, B_mod, W_C, b_C, C_mod, xconv, Bbuf, Cbuf);

  scan_k<<<dim3(32), 256, 0, stream>>>(xconv, gatep, Bbuf, Cbuf, A_log, Dp, ybuf);

  gemm_bt<0,0><<<dim3(D_MODEL/128, ML/128), 256, 0, stream>>>(
      (const void*)ybuf, Wt_out, b_out, nullptr, nullptr, out, ML, D_MODEL, D_INNER);
}

// Round 4
// 811.781 us; speedup vs baseline: 1.9743x; 1.9743x over previous
//
#include <hip/hip_runtime.h>
#include <stdint.h>

#define D_MODEL 1024
#define D_STATE 16
#define D_INNER 2048
#define BATCH   4
#define SEQ     2048
#define ML      (BATCH*SEQ)   // 8192 rows
#define CH      64
#define NCHUNK  (SEQ/CH)      // 32

typedef unsigned short u16;
typedef u16   u16x8  __attribute__((ext_vector_type(8)));
typedef short s16x8  __attribute__((ext_vector_type(8)));
typedef float f32x4  __attribute__((ext_vector_type(4)));

__device__ __forceinline__ float b2f(u16 u){
  union { uint32_t i; float f; } v; v.i = ((uint32_t)u) << 16; return v.f;
}
__device__ __forceinline__ u16 f2b(float f){
  uint32_t x = __float_as_uint(f);
  return (u16)((x + 0x7fffu + ((x >> 16) & 1u)) >> 16);   // RNE
}
__device__ __forceinline__ float silu_f(float v){
  return v / (1.f + __expf(-v));
}

// ------------- transpose + cast: in f32 (R x C) -> out bf16 (C x R) -------------
__global__ __launch_bounds__(256) void transpose_cast_k(const float* __restrict__ in,
                                                        u16* __restrict__ out,
                                                        int R, int C){
  __shared__ float tile[32][33];
  int bx = blockIdx.x * 32, by = blockIdx.y * 32;
  int tx = threadIdx.x & 31, ty = threadIdx.x >> 5;
  #pragma unroll
  for (int i = 0; i < 32; i += 8)
    tile[ty + i][tx] = in[(size_t)(by + ty + i) * C + bx + tx];
  __syncthreads();
  #pragma unroll
  for (int i = 0; i < 32; i += 8)
    out[(size_t)(bx + ty + i) * R + by + tx] = f2b(tile[tx][ty + i]);
}

// ------------- elementwise cast f32 -> bf16 (8 per thread) -------------
__global__ __launch_bounds__(256) void cast_k(const float* __restrict__ in,
                                              u16* __restrict__ out){
  size_t i = ((size_t)blockIdx.x * 256 + threadIdx.x) * 8;
  f32x4 a = *(const f32x4*)(in + i);
  f32x4 b = *(const f32x4*)(in + i + 4);
  u16x8 o;
  #pragma unroll
  for (int j = 0; j < 4; ++j){ o[j] = f2b(a[j]); o[4+j] = f2b(b[j]); }
  *(u16x8*)(out + i) = o;
}

// ------------- MFMA GEMM: D = A(MxK) * Bt(NxK)^T (+bias, epilogue) -------------
// AF32: A source is f32 (converted to bf16 during LDS staging); else bf16.
// MODE 0: outf[row*N+col] = f32(acc + bias[col])          (final output, f32)
// MODE 1: s = silu(acc + bias[col]); col<N/2 -> out0 bf16 (x_ssm), else out1 bf16 (gate)
template<int MODE, int AF32>
__global__ __launch_bounds__(256) void gemm_bt(const void* __restrict__ Av,
                                               const u16* __restrict__ Bt,
                                               const float* __restrict__ bias,
                                               u16* __restrict__ out0,
                                               u16* __restrict__ out1,
                                               float* __restrict__ outf,
                                               int M, int N, int K){
  __shared__ __align__(16) u16 Asb[128*40];
  __shared__ __align__(16) u16 Bsb[128*40];
  const int t    = threadIdx.x;
  const int n0   = blockIdx.x * 128;
  const int m0   = blockIdx.y * 128;
  const int wave = t >> 6, lane = t & 63;
  const int wm   = (wave >> 1) * 64, wn = (wave & 1) * 64;
  const int lrow = lane & 15, kq = (lane >> 4) * 8;

  f32x4 acc[4][4];
  #pragma unroll
  for (int i = 0; i < 4; ++i)
    #pragma unroll
    for (int j = 0; j < 4; ++j)
      acc[i][j] = (f32x4){0.f, 0.f, 0.f, 0.f};

  for (int k0 = 0; k0 < K; k0 += 32) {
    if (AF32) {
      const float* A = (const float*)Av;
      int r = t >> 1, c = (t & 1) * 16;
      const float* src = A + (size_t)(m0 + r) * K + k0 + c;
      f32x4 v0 = *(const f32x4*)(src);
      f32x4 v1 = *(const f32x4*)(src + 4);
      f32x4 v2 = *(const f32x4*)(src + 8);
      f32x4 v3 = *(const f32x4*)(src + 12);
      u16x8 p0, p1;
      #pragma unroll
      for (int j = 0; j < 4; ++j){
        p0[j]   = f2b(v0[j]); p0[4+j] = f2b(v1[j]);
        p1[j]   = f2b(v2[j]); p1[4+j] = f2b(v3[j]);
      }
      *(u16x8*)&Asb[r*40 + c]     = p0;
      *(u16x8*)&Asb[r*40 + c + 8] = p1;
    } else {
      const u16* A = (const u16*)Av;
      #pragma unroll
      for (int i = 0; i < 2; ++i) {
        int f = (i*256 + t) * 8;
        int r = f >> 5, c = f & 31;
        *(u16x8*)&Asb[r*40 + c] = *(const u16x8*)&A[(size_t)(m0 + r)*K + k0 + c];
      }
    }
    #pragma unroll
    for (int i = 0; i < 2; ++i) {
      int f = (i*256 + t) * 8;
      int r = f >> 5, c = f & 31;
      *(u16x8*)&Bsb[r*40 + c] = *(const u16x8*)&Bt[(size_t)(n0 + r)*K + k0 + c];
    }
    __syncthreads();
    s16x8 af[4], bfr[4];
    #pragma unroll
    for (int i = 0; i < 4; ++i) af[i]  = *(const s16x8*)&Asb[(wm + i*16 + lrow)*40 + kq];
    #pragma unroll
    for (int j = 0; j < 4; ++j) bfr[j] = *(const s16x8*)&Bsb[(wn + j*16 + lrow)*40 + kq];
    #pragma unroll
    for (int i = 0; i < 4; ++i)
      #pragma unroll
      for (int j = 0; j < 4; ++j)
        acc[i][j] = __builtin_amdgcn_mfma_f32_16x16x32_bf16(af[i], bfr[j], acc[i][j], 0, 0, 0);
    __syncthreads();
  }

  const int Nh = N >> 1;
  #pragma unroll
  for (int i = 0; i < 4; ++i) {
    #pragma unroll
    for (int j = 0; j < 4; ++j) {
      int col = n0 + wn + j*16 + lrow;
      float bv = bias[col];
      #pragma unroll
      for (int r = 0; r < 4; ++r) {
        int row = m0 + wm + i*16 + (lane >> 4)*4 + r;   // C/D: col=lane&15, row=quad*4+reg
        float v = acc[i][j][r] + bv;
        if (MODE == 0) {
          outf[(size_t)row * N + col] = v;
        } else {
          float s = silu_f(v);
          if (col < Nh) out0[(size_t)row * Nh + col]        = f2b(s);
          else          out1[(size_t)row * Nh + (col - Nh)] = f2b(s);
        }
      }
    }
  }
}

// ------------- conv(3, depthwise) + B/C projections -------------
__global__ __launch_bounds__(256) void conv_bc_k(const u16* __restrict__ xs,
    const float* __restrict__ conv_w, const float* __restrict__ conv_b,
    const float* __restrict__ W_B, const float* __restrict__ b_B, const float* __restrict__ B_mod,
    const float* __restrict__ W_C, const float* __restrict__ b_C, const float* __restrict__ C_mod,
    u16* __restrict__ xconv, float* __restrict__ Bbuf, float* __restrict__ Cbuf){
  int bl = blockIdx.x;
  int b = bl >> 11, l = bl & (SEQ-1);
  int t = threadIdx.x;
  int d = t * 8;
  const u16* row0 = xs + (size_t)bl * D_INNER + d;

  float f0[8], fm[8], fp[8];
  { u16x8 v = *(const u16x8*)row0;
    #pragma unroll
    for (int j = 0; j < 8; ++j) f0[j] = b2f(v[j]); }
  if (l > 0) {
    u16x8 v = *(const u16x8*)(row0 - D_INNER);
    #pragma unroll
    for (int j = 0; j < 8; ++j) fm[j] = b2f(v[j]);
  } else {
    #pragma unroll
    for (int j = 0; j < 8; ++j) fm[j] = 0.f;
  }
  if (l < SEQ-1) {
    u16x8 v = *(const u16x8*)(row0 + D_INNER);
    #pragma unroll
    for (int j = 0; j < 8; ++j) fp[j] = b2f(v[j]);
  } else {
    #pragma unroll
    for (int j = 0; j < 8; ++j) fp[j] = 0.f;
  }

  const float* wp = conv_w + (size_t)d * 3;
  float wl[24];
  #pragma unroll
  for (int q = 0; q < 6; ++q){
    f32x4 v = *(const f32x4*)(wp + q*4);
    #pragma unroll
    for (int j = 0; j < 4; ++j) wl[q*4 + j] = v[j];
  }
  float cb[8];
  { f32x4 c0 = *(const f32x4*)(conv_b + d), c1 = *(const f32x4*)(conv_b + d + 4);
    #pragma unroll
    for (int j = 0; j < 4; ++j){ cb[j] = c0[j]; cb[4+j] = c1[j]; } }

  float xc[8];
  #pragma unroll
  for (int j = 0; j < 8; ++j)
    xc[j] = wl[3*j]*fm[j] + wl[3*j+1]*f0[j] + wl[3*j+2]*fp[j] + cb[j];

  u16x8 o;
  #pragma unroll
  for (int j = 0; j < 8; ++j) o[j] = f2b(xc[j]);
  *(u16x8*)(xconv + (size_t)bl * D_INNER + d) = o;

  float sB[16], sC[16];
  #pragma unroll
  for (int s = 0; s < 16; ++s){ sB[s]=0.f; sC[s]=0.f; }
  #pragma unroll
  for (int j = 0; j < 8; ++j){
    const float* wb = W_B + (size_t)(d+j)*16;
    const float* wc = W_C + (size_t)(d+j)*16;
    #pragma unroll
    for (int q = 0; q < 4; ++q){
      f32x4 vb = *(const f32x4*)(wb + q*4);
      f32x4 vc = *(const f32x4*)(wc + q*4);
      #pragma unroll
      for (int s = 0; s < 4; ++s){
        sB[q*4+s] += xc[j]*vb[s];
        sC[q*4+s] += xc[j]*vc[s];
      }
    }
  }
  #pragma unroll
  for (int m = 1; m < 64; m <<= 1){
    #pragma unroll
    for (int s = 0; s < 16; ++s){
      sB[s] += __shfl_xor(sB[s], m, 64);
      sC[s] += __shfl_xor(sC[s], m, 64);
    }
  }
  __shared__ float red[4][32];
  int wave = t >> 6, lane = t & 63;
  if (lane == 0){
    #pragma unroll
    for (int s = 0; s < 16; ++s){ red[wave][s] = sB[s]; red[wave][16+s] = sC[s]; }
  }
  __syncthreads();
  if (t < 16){
    float v = red[0][t]+red[1][t]+red[2][t]+red[3][t] + b_B[t] + B_mod[b*16+t];
    Bbuf[(size_t)bl*16 + t] = v;
  } else if (t < 32){
    int s = t - 16;
    float v = red[0][16+s]+red[1][16+s]+red[2][16+s]+red[3][16+s] + b_C[s] + C_mod[b*16+s];
    Cbuf[(size_t)bl*16 + s] = v;
  }
}

// ------------- chunked scan, pass 1: local chunk-final states -------------
// grid (NCHUNK, D_INNER/256, BATCH); h starts at 0; writes hend[b][c][d][16]
__global__ __launch_bounds__(256) void state_k(const u16* __restrict__ xconv,
    const float* __restrict__ Bbuf, const float* __restrict__ A_log,
    float* __restrict__ hend){
  int c = blockIdx.x, db = blockIdx.y, b = blockIdx.z;
  int d = db*256 + threadIdx.x;

  float Abar[16];
  #pragma unroll
  for (int s = 0; s < 16; ++s)
    Abar[s] = __expf(-0.1f * __expf(A_log[d*16 + s]));
  float h[16];
  #pragma unroll
  for (int s = 0; s < 16; ++s) h[s] = 0.f;

  size_t base = (size_t)b * SEQ * D_INNER + (size_t)c * CH * D_INNER + d;
  const float* Br = Bbuf + ((size_t)b * SEQ + (size_t)c * CH) * 16;

  float Bc[16];
  #pragma unroll
  for (int s = 0; s < 16; ++s) Bc[s] = Br[s];
  float xn = b2f(xconv[base]);

  for (int l = 0; l < CH; ++l){
    float x = xn;
    float Bl[16];
    #pragma unroll
    for (int s = 0; s < 16; ++s) Bl[s] = Bc[s];
    if (l < CH-1){
      xn = b2f(xconv[base + (size_t)(l+1)*D_INNER]);
      #pragma unroll
      for (int s = 0; s < 16; ++s) Bc[s] = Br[(l+1)*16 + s];
    }
    #pragma unroll
    for (int s = 0; s < 16; ++s)
      h[s] = Abar[s]*h[s] + x*Bl[s];
  }
  float* hp = hend + (((size_t)(b*NCHUNK + c))*D_INNER + d)*16;
  #pragma unroll
  for (int q = 0; q < 4; ++q)
    *(f32x4*)(hp + q*4) = (f32x4){h[q*4], h[q*4+1], h[q*4+2], h[q*4+3]};
}

// ------------- chunked scan, pass 2: prefix across chunks -------------
// one thread per (b,d,s): hin[c] = state entering chunk c
__global__ __launch_bounds__(256) void prefix_k(const float* __restrict__ hend,
    const float* __restrict__ A_log, float* __restrict__ hin){
  int g = blockIdx.x*256 + threadIdx.x;        // 0..BATCH*D_INNER*16-1
  int s = g & 15;
  int d = (g >> 4) & (D_INNER-1);
  int b = g >> 15;
  float decay = __expf(-0.1f * (float)CH * __expf(A_log[d*16 + s]));
  size_t stride = (size_t)D_INNER * 16;
  const float* he = hend + (size_t)b*NCHUNK*stride + (size_t)d*16 + s;
  float*       hi = hin  + (size_t)b*NCHUNK*stride + (size_t)d*16 + s;
  float h = 0.f;
  for (int c0 = 0; c0 < NCHUNK; c0 += 8){
    float v[8];
    #pragma unroll
    for (int i = 0; i < 8; ++i) v[i] = he[(size_t)(c0+i)*stride];
    #pragma unroll
    for (int i = 0; i < 8; ++i){
      hi[(size_t)(c0+i)*stride] = h;
      h = decay*h + v[i];
    }
  }
}

// ------------- chunked scan, pass 3: full scan per chunk from hin -------------
__global__ __launch_bounds__(256) void scan2_k(const u16* __restrict__ xconv,
    const u16* __restrict__ gate, const float* __restrict__ Bbuf, const float* __restrict__ Cbuf,
    const float* __restrict__ A_log, const float* __restrict__ Dp,
    const float* __restrict__ hin, u16* __restrict__ ybuf){
  int c = blockIdx.x, db = blockIdx.y, b = blockIdx.z;
  int d = db*256 + threadIdx.x;

  float Abar[16];
  #pragma unroll
  for (int s = 0; s < 16; ++s)
    Abar[s] = __expf(-0.1f * __expf(A_log[d*16 + s]));
  float h[16];
  const float* hp = hin + (((size_t)(b*NCHUNK + c))*D_INNER + d)*16;
  #pragma unroll
  for (int q = 0; q < 4; ++q){
    f32x4 v = *(const f32x4*)(hp + q*4);
    #pragma unroll
    for (int j = 0; j < 4; ++j) h[q*4 + j] = v[j];
  }
  float Dd = Dp[d];

  size_t base = (size_t)b * SEQ * D_INNER + (size_t)c * CH * D_INNER + d;
  const float* Br = Bbuf + ((size_t)b * SEQ + (size_t)c * CH) * 16;
  const float* Cr = Cbuf + ((size_t)b * SEQ + (size_t)c * CH) * 16;

  float Bc[16], Cc[16];
  #pragma unroll
  for (int s = 0; s < 16; ++s){ Bc[s] = Br[s]; Cc[s] = Cr[s]; }
  float xn = b2f(xconv[base]);
  float gn = b2f(gate[base]);

  for (int l = 0; l < CH; ++l){
    float x = xn, g = gn;
    float Bl[16], Cl[16];
    #pragma unroll
    for (int s = 0; s < 16; ++s){ Bl[s] = Bc[s]; Cl[s] = Cc[s]; }
    if (l < CH-1){
      size_t idx = base + (size_t)(l+1)*D_INNER;
      xn = b2f(xconv[idx]); gn = b2f(gate[idx]);
      #pragma unroll
      for (int s = 0; s < 16; ++s){ Bc[s] = Br[(l+1)*16 + s]; Cc[s] = Cr[(l+1)*16 + s]; }
    }
    float ya[4] = {0.f, 0.f, 0.f, 0.f};
    #pragma unroll
    for (int s = 0; s < 16; ++s){
      float hv = Abar[s]*h[s] + x*Bl[s];
      h[s] = hv;
      ya[s & 3] += hv * Cl[s];
    }
    float y = ((ya[0]+ya[1]) + (ya[2]+ya[3]) + Dd*x) * g;
    ybuf[base + (size_t)l*D_INNER] = f2b(y);
  }
}

extern "C" void kernel_launch(void* const* d_in, const int* in_sizes, int n_in,
                              void* d_out, int out_size, void* d_ws, size_t ws_size,
                              hipStream_t stream){
  const float* x      = (const float*)d_in[0];
  const float* B_mod  = (const float*)d_in[1];
  const float* C_mod  = (const float*)d_in[2];
  const float* W_in   = (const float*)d_in[3];
  const float* b_in   = (const float*)d_in[4];
  const float* conv_w = (const float*)d_in[5];
  const float* conv_b = (const float*)d_in[6];
  const float* A_log  = (const float*)d_in[7];
  const float* Dp     = (const float*)d_in[8];
  const float* W_B    = (const float*)d_in[9];
  const float* b_B    = (const float*)d_in[10];
  const float* W_C    = (const float*)d_in[11];
  const float* b_C    = (const float*)d_in[12];
  const float* W_out  = (const float*)d_in[13];
  const float* b_out  = (const float*)d_in[14];
  float* out = (float*)d_out;   // reference output dtype is float32

  char* ws = (char*)d_ws;
  size_t off = 0;
  auto alloc = [&](size_t bytes)->char* {
    char* p = ws + off; off += (bytes + 255) & ~(size_t)255; return p;
  };
  u16* Wt_in  = (u16*)alloc((size_t)(2*D_INNER)*D_MODEL*2); // 4096x1024 bf16
  u16* Wt_out = (u16*)alloc((size_t)D_MODEL*D_INNER*2);     // 1024x2048 bf16
  u16* xs     = (u16*)alloc((size_t)ML*D_INNER*2);          // x_ssm_silu; reused as y
  u16* gatep  = (u16*)alloc((size_t)ML*D_INNER*2);          // silu(x_res)
  u16* xconv  = (u16*)alloc((size_t)ML*D_INNER*2);
  float* Bbuf = (float*)alloc((size_t)ML*D_STATE*4);
  float* Cbuf = (float*)alloc((size_t)ML*D_STATE*4);
  u16* xbf    = (u16*)alloc((size_t)ML*D_MODEL*2);          // x cast to bf16; dead after gemm1
  float* hin  = (float*)alloc((size_t)BATCH*NCHUNK*D_INNER*16*4);
  float* hend = (float*)xbf;   // reuse: xbf dead before state_k (16.78 MB fits)
  u16* ybuf = xs;              // xs dead after conv_bc_k

  transpose_cast_k<<<dim3((2*D_INNER)/32, D_MODEL/32), 256, 0, stream>>>(W_in, Wt_in, D_MODEL, 2*D_INNER);
  transpose_cast_k<<<dim3(D_MODEL/32, D_INNER/32),     256, 0, stream>>>(W_out, Wt_out, D_INNER, D_MODEL);
  cast_k<<<dim3((ML*D_MODEL)/(256*8)), 256, 0, stream>>>(x, xbf);

  gemm_bt<1,0><<<dim3((2*D_INNER)/128, ML/128), 256, 0, stream>>>(
      (const void*)xbf, Wt_in, b_in, xs, gatep, nullptr, ML, 2*D_INNER, D_MODEL);

  conv_bc_k<<<dim3(ML), 256, 0, stream>>>(
      xs, conv_w, conv_b, W_B, b_B, B_mod, W_C, b_C, C_mod, xconv, Bbuf, Cbuf);

  state_k<<<dim3(NCHUNK, D_INNER/256, BATCH), 256, 0, stream>>>(xconv, Bbuf, A_log, hend);
  prefix_k<<<dim3((BATCH*D_INNER*16)/256), 256, 0, stream>>>(hend, A_log, hin);
  scan2_k<<<dim3(NCHUNK, D_INNER/256, BATCH), 256, 0, stream>>>(
      xconv, gatep, Bbuf, Cbuf, A_log, Dp, hin, ybuf);

  gemm_bt<0,0><<<dim3(D_MODEL/128, ML/128), 256, 0, stream>>>(
      (const void*)ybuf, Wt_out, b_out, nullptr, nullptr, out, ML, D_MODEL, D_INNER);
}

// Round 5
// 403.803 us; speedup vs baseline: 3.9690x; 2.0103x over previous
//
#include <hip/hip_runtime.h>
#include <stdint.h>

#define D_MODEL 1024
#define D_STATE 16
#define D_INNER 2048
#define BATCH   4
#define SEQ     2048
#define ML      (BATCH*SEQ)   // 8192 rows
#define CH      64
#define NCHUNK  (SEQ/CH)      // 32
#define KSEG    8             // K-split for B/C projection GEMM

typedef unsigned short u16;
typedef u16   u16x8  __attribute__((ext_vector_type(8)));
typedef short s16x8  __attribute__((ext_vector_type(8)));
typedef float f32x4  __attribute__((ext_vector_type(4)));

__device__ __forceinline__ float b2f(u16 u){
  union { uint32_t i; float f; } v; v.i = ((uint32_t)u) << 16; return v.f;
}
__device__ __forceinline__ u16 f2b(float f){
  uint32_t x = __float_as_uint(f);
  return (u16)((x + 0x7fffu + ((x >> 16) & 1u)) >> 16);   // RNE
}
__device__ __forceinline__ float silu_f(float v){
  return v / (1.f + __expf(-v));
}

// ------------- transpose + cast: in f32 (R x C) -> out bf16 (C x R) -------------
__global__ __launch_bounds__(256) void transpose_cast_k(const float* __restrict__ in,
                                                        u16* __restrict__ out,
                                                        int R, int C){
  __shared__ float tile[32][33];
  int bx = blockIdx.x * 32, by = blockIdx.y * 32;
  int tx = threadIdx.x & 31, ty = threadIdx.x >> 5;
  #pragma unroll
  for (int i = 0; i < 32; i += 8)
    tile[ty + i][tx] = in[(size_t)(by + ty + i) * C + bx + tx];
  __syncthreads();
  #pragma unroll
  for (int i = 0; i < 32; i += 8)
    out[(size_t)(bx + ty + i) * R + by + tx] = f2b(tile[tx][ty + i]);
}

// ------------- elementwise cast f32 -> bf16 (8 per thread) -------------
__global__ __launch_bounds__(256) void cast_k(const float* __restrict__ in,
                                              u16* __restrict__ out){
  size_t i = ((size_t)blockIdx.x * 256 + threadIdx.x) * 8;
  f32x4 a = *(const f32x4*)(in + i);
  f32x4 b = *(const f32x4*)(in + i + 4);
  u16x8 o;
  #pragma unroll
  for (int j = 0; j < 4; ++j){ o[j] = f2b(a[j]); o[4+j] = f2b(b[j]); }
  *(u16x8*)(out + i) = o;
}

// ------------- W_B|W_C (2048x16 f32 each) -> Wt_bc bf16 32x2048 -------------
// row n<16: W_B column n; row n>=16: W_C column n-16
__global__ __launch_bounds__(256) void bc_wt_k(const float* __restrict__ W_B,
                                               const float* __restrict__ W_C,
                                               u16* __restrict__ Wt){
  int n = blockIdx.y;                          // 0..31
  int k = blockIdx.x * 256 + threadIdx.x;      // 0..2047
  const float* src = (n < 16) ? W_B : W_C;
  Wt[(size_t)n * D_INNER + k] = f2b(src[(size_t)k * 16 + (n & 15)]);
}

// ------------- MFMA GEMM: D = A(MxK) * Bt(NxK)^T (+bias, epilogue) -------------
// AF32: A source is f32 (converted to bf16 during LDS staging); else bf16.
// MODE 0: outf[row*N+col] = f32(acc + bias[col])          (final output, f32)
// MODE 1: s = silu(acc + bias[col]); col<N/2 -> out0 bf16 (x_ssm), else out1 bf16 (gate)
template<int MODE, int AF32>
__global__ __launch_bounds__(256) void gemm_bt(const void* __restrict__ Av,
                                               const u16* __restrict__ Bt,
                                               const float* __restrict__ bias,
                                               u16* __restrict__ out0,
                                               u16* __restrict__ out1,
                                               float* __restrict__ outf,
                                               int M, int N, int K){
  __shared__ __align__(16) u16 Asb[128*40];
  __shared__ __align__(16) u16 Bsb[128*40];
  const int t    = threadIdx.x;
  const int n0   = blockIdx.x * 128;
  const int m0   = blockIdx.y * 128;
  const int wave = t >> 6, lane = t & 63;
  const int wm   = (wave >> 1) * 64, wn = (wave & 1) * 64;
  const int lrow = lane & 15, kq = (lane >> 4) * 8;

  f32x4 acc[4][4];
  #pragma unroll
  for (int i = 0; i < 4; ++i)
    #pragma unroll
    for (int j = 0; j < 4; ++j)
      acc[i][j] = (f32x4){0.f, 0.f, 0.f, 0.f};

  for (int k0 = 0; k0 < K; k0 += 32) {
    if (AF32) {
      const float* A = (const float*)Av;
      int r = t >> 1, c = (t & 1) * 16;
      const float* src = A + (size_t)(m0 + r) * K + k0 + c;
      f32x4 v0 = *(const f32x4*)(src);
      f32x4 v1 = *(const f32x4*)(src + 4);
      f32x4 v2 = *(const f32x4*)(src + 8);
      f32x4 v3 = *(const f32x4*)(src + 12);
      u16x8 p0, p1;
      #pragma unroll
      for (int j = 0; j < 4; ++j){
        p0[j]   = f2b(v0[j]); p0[4+j] = f2b(v1[j]);
        p1[j]   = f2b(v2[j]); p1[4+j] = f2b(v3[j]);
      }
      *(u16x8*)&Asb[r*40 + c]     = p0;
      *(u16x8*)&Asb[r*40 + c + 8] = p1;
    } else {
      const u16* A = (const u16*)Av;
      #pragma unroll
      for (int i = 0; i < 2; ++i) {
        int f = (i*256 + t) * 8;
        int r = f >> 5, c = f & 31;
        *(u16x8*)&Asb[r*40 + c] = *(const u16x8*)&A[(size_t)(m0 + r)*K + k0 + c];
      }
    }
    #pragma unroll
    for (int i = 0; i < 2; ++i) {
      int f = (i*256 + t) * 8;
      int r = f >> 5, c = f & 31;
      *(u16x8*)&Bsb[r*40 + c] = *(const u16x8*)&Bt[(size_t)(n0 + r)*K + k0 + c];
    }
    __syncthreads();
    s16x8 af[4], bfr[4];
    #pragma unroll
    for (int i = 0; i < 4; ++i) af[i]  = *(const s16x8*)&Asb[(wm + i*16 + lrow)*40 + kq];
    #pragma unroll
    for (int j = 0; j < 4; ++j) bfr[j] = *(const s16x8*)&Bsb[(wn + j*16 + lrow)*40 + kq];
    #pragma unroll
    for (int i = 0; i < 4; ++i)
      #pragma unroll
      for (int j = 0; j < 4; ++j)
        acc[i][j] = __builtin_amdgcn_mfma_f32_16x16x32_bf16(af[i], bfr[j], acc[i][j], 0, 0, 0);
    __syncthreads();
  }

  const int Nh = N >> 1;
  #pragma unroll
  for (int i = 0; i < 4; ++i) {
    #pragma unroll
    for (int j = 0; j < 4; ++j) {
      int col = n0 + wn + j*16 + lrow;
      float bv = bias[col];
      #pragma unroll
      for (int r = 0; r < 4; ++r) {
        int row = m0 + wm + i*16 + (lane >> 4)*4 + r;   // C/D: col=lane&15, row=quad*4+reg
        float v = acc[i][j][r] + bv;
        if (MODE == 0) {
          outf[(size_t)row * N + col] = v;
        } else {
          float s = silu_f(v);
          if (col < Nh) out0[(size_t)row * Nh + col]        = f2b(s);
          else          out1[(size_t)row * Nh + (col - Nh)] = f2b(s);
        }
      }
    }
  }
}

// ------------- depthwise conv(3) only -------------
__global__ __launch_bounds__(256) void conv_k(const u16* __restrict__ xs,
    const float* __restrict__ conv_w, const float* __restrict__ conv_b,
    u16* __restrict__ xconv){
  int bl = blockIdx.x;
  int l = bl & (SEQ-1);
  int d = threadIdx.x * 8;
  const u16* row0 = xs + (size_t)bl * D_INNER + d;

  float f0[8], fm[8], fp[8];
  { u16x8 v = *(const u16x8*)row0;
    #pragma unroll
    for (int j = 0; j < 8; ++j) f0[j] = b2f(v[j]); }
  if (l > 0) {
    u16x8 v = *(const u16x8*)(row0 - D_INNER);
    #pragma unroll
    for (int j = 0; j < 8; ++j) fm[j] = b2f(v[j]);
  } else {
    #pragma unroll
    for (int j = 0; j < 8; ++j) fm[j] = 0.f;
  }
  if (l < SEQ-1) {
    u16x8 v = *(const u16x8*)(row0 + D_INNER);
    #pragma unroll
    for (int j = 0; j < 8; ++j) fp[j] = b2f(v[j]);
  } else {
    #pragma unroll
    for (int j = 0; j < 8; ++j) fp[j] = 0.f;
  }

  const float* wp = conv_w + (size_t)d * 3;   // 24 f32, L1-resident (24 KB total)
  float wl[24];
  #pragma unroll
  for (int q = 0; q < 6; ++q){
    f32x4 v = *(const f32x4*)(wp + q*4);
    #pragma unroll
    for (int j = 0; j < 4; ++j) wl[q*4 + j] = v[j];
  }
  float cb[8];
  { f32x4 c0 = *(const f32x4*)(conv_b + d), c1 = *(const f32x4*)(conv_b + d + 4);
    #pragma unroll
    for (int j = 0; j < 4; ++j){ cb[j] = c0[j]; cb[4+j] = c1[j]; } }

  u16x8 o;
  #pragma unroll
  for (int j = 0; j < 8; ++j)
    o[j] = f2b(wl[3*j]*fm[j] + wl[3*j+1]*f0[j] + wl[3*j+2]*fp[j] + cb[j]);
  *(u16x8*)(xconv + (size_t)bl * D_INNER + d) = o;
}

// ------------- B/C projection GEMM: xconv(8192x2048) @ Wt_bc^T(32x2048) ------
// grid (KSEG, M/128); K-split partials -> partial[kseg][row][32]
__global__ __launch_bounds__(256) void bc_gemm_k(const u16* __restrict__ xconv,
                                                 const u16* __restrict__ Wt,
                                                 float* __restrict__ partial){
  __shared__ __align__(16) u16 Asb[128*40];
  __shared__ __align__(16) u16 Wsb[32*40];
  const int kseg = blockIdx.x;
  const int m0   = blockIdx.y * 128;
  const int t    = threadIdx.x;
  const int wave = t >> 6, lane = t & 63;
  const int wm   = wave * 32;
  const int lrow = lane & 15, kq = (lane >> 4) * 8;

  f32x4 acc[2][2];
  #pragma unroll
  for (int i = 0; i < 2; ++i)
    #pragma unroll
    for (int j = 0; j < 2; ++j)
      acc[i][j] = (f32x4){0.f, 0.f, 0.f, 0.f};

  const int kbase = kseg * (D_INNER / KSEG);   // 256-wide K segment
  for (int ks = 0; ks < (D_INNER / KSEG); ks += 32) {
    int k0 = kbase + ks;
    #pragma unroll
    for (int i = 0; i < 2; ++i) {
      int f = (i*256 + t) * 8;
      int r = f >> 5, c = f & 31;
      *(u16x8*)&Asb[r*40 + c] = *(const u16x8*)&xconv[(size_t)(m0 + r)*D_INNER + k0 + c];
    }
    if (t < 128) {
      int f = t * 8;
      int r = f >> 5, c = f & 31;
      *(u16x8*)&Wsb[r*40 + c] = *(const u16x8*)&Wt[(size_t)r*D_INNER + k0 + c];
    }
    __syncthreads();
    s16x8 af[2], wf[2];
    #pragma unroll
    for (int i = 0; i < 2; ++i) af[i] = *(const s16x8*)&Asb[(wm + i*16 + lrow)*40 + kq];
    #pragma unroll
    for (int j = 0; j < 2; ++j) wf[j] = *(const s16x8*)&Wsb[(j*16 + lrow)*40 + kq];
    #pragma unroll
    for (int i = 0; i < 2; ++i)
      #pragma unroll
      for (int j = 0; j < 2; ++j)
        acc[i][j] = __builtin_amdgcn_mfma_f32_16x16x32_bf16(af[i], wf[j], acc[i][j], 0, 0, 0);
    __syncthreads();
  }

  #pragma unroll
  for (int i = 0; i < 2; ++i)
    #pragma unroll
    for (int j = 0; j < 2; ++j)
      #pragma unroll
      for (int r = 0; r < 4; ++r) {
        int row = m0 + wm + i*16 + (lane >> 4)*4 + r;
        int col = j*16 + lrow;
        partial[((size_t)kseg * ML + row) * 32 + col] = acc[i][j][r];
      }
}

// ------------- reduce partials + bias + mod -> Bbuf/Cbuf -------------
__global__ __launch_bounds__(256) void bc_reduce_k(const float* __restrict__ partial,
    const float* __restrict__ b_B, const float* __restrict__ B_mod,
    const float* __restrict__ b_C, const float* __restrict__ C_mod,
    float* __restrict__ Bbuf, float* __restrict__ Cbuf){
  int g = blockIdx.x * 256 + threadIdx.x;   // < ML*32
  int row = g >> 5, col = g & 31;
  int b = row >> 11;
  float s = 0.f;
  #pragma unroll
  for (int seg = 0; seg < KSEG; ++seg)
    s += partial[(size_t)seg * ML * 32 + g];
  if (col < 16) Bbuf[(size_t)row*16 + col]      = s + b_B[col]      + B_mod[b*16 + col];
  else          Cbuf[(size_t)row*16 + col - 16] = s + b_C[col - 16] + C_mod[b*16 + col - 16];
}

// ------------- chunked scan, pass 1: local chunk-final states -------------
__global__ __launch_bounds__(256) void state_k(const u16* __restrict__ xconv,
    const float* __restrict__ Bbuf, const float* __restrict__ A_log,
    float* __restrict__ hend){
  int c = blockIdx.x, db = blockIdx.y, b = blockIdx.z;
  int d = db*256 + threadIdx.x;

  float Abar[16];
  #pragma unroll
  for (int s = 0; s < 16; ++s)
    Abar[s] = __expf(-0.1f * __expf(A_log[d*16 + s]));
  float h[16];
  #pragma unroll
  for (int s = 0; s < 16; ++s) h[s] = 0.f;

  size_t base = (size_t)b * SEQ * D_INNER + (size_t)c * CH * D_INNER + d;
  const float* Br = Bbuf + ((size_t)b * SEQ + (size_t)c * CH) * 16;

  float Bc[16];
  #pragma unroll
  for (int s = 0; s < 16; ++s) Bc[s] = Br[s];
  float xn = b2f(xconv[base]);

  for (int l = 0; l < CH; ++l){
    float x = xn;
    float Bl[16];
    #pragma unroll
    for (int s = 0; s < 16; ++s) Bl[s] = Bc[s];
    if (l < CH-1){
      xn = b2f(xconv[base + (size_t)(l+1)*D_INNER]);
      #pragma unroll
      for (int s = 0; s < 16; ++s) Bc[s] = Br[(l+1)*16 + s];
    }
    #pragma unroll
    for (int s = 0; s < 16; ++s)
      h[s] = Abar[s]*h[s] + x*Bl[s];
  }
  float* hp = hend + (((size_t)(b*NCHUNK + c))*D_INNER + d)*16;
  #pragma unroll
  for (int q = 0; q < 4; ++q)
    *(f32x4*)(hp + q*4) = (f32x4){h[q*4], h[q*4+1], h[q*4+2], h[q*4+3]};
}

// ------------- chunked scan, pass 2: prefix across chunks -------------
__global__ __launch_bounds__(256) void prefix_k(const float* __restrict__ hend,
    const float* __restrict__ A_log, float* __restrict__ hin){
  int g = blockIdx.x*256 + threadIdx.x;
  int s = g & 15;
  int d = (g >> 4) & (D_INNER-1);
  int b = g >> 15;
  float decay = __expf(-0.1f * (float)CH * __expf(A_log[d*16 + s]));
  size_t stride = (size_t)D_INNER * 16;
  const float* he = hend + (size_t)b*NCHUNK*stride + (size_t)d*16 + s;
  float*       hi = hin  + (size_t)b*NCHUNK*stride + (size_t)d*16 + s;
  float h = 0.f;
  for (int c0 = 0; c0 < NCHUNK; c0 += 8){
    float v[8];
    #pragma unroll
    for (int i = 0; i < 8; ++i) v[i] = he[(size_t)(c0+i)*stride];
    #pragma unroll
    for (int i = 0; i < 8; ++i){
      hi[(size_t)(c0+i)*stride] = h;
      h = decay*h + v[i];
    }
  }
}

// ------------- chunked scan, pass 3: full scan per chunk from hin -------------
__global__ __launch_bounds__(256) void scan2_k(const u16* __restrict__ xconv,
    const u16* __restrict__ gate, const float* __restrict__ Bbuf, const float* __restrict__ Cbuf,
    const float* __restrict__ A_log, const float* __restrict__ Dp,
    const float* __restrict__ hin, u16* __restrict__ ybuf){
  int c = blockIdx.x, db = blockIdx.y, b = blockIdx.z;
  int d = db*256 + threadIdx.x;

  float Abar[16];
  #pragma unroll
  for (int s = 0; s < 16; ++s)
    Abar[s] = __expf(-0.1f * __expf(A_log[d*16 + s]));
  float h[16];
  const float* hp = hin + (((size_t)(b*NCHUNK + c))*D_INNER + d)*16;
  #pragma unroll
  for (int q = 0; q < 4; ++q){
    f32x4 v = *(const f32x4*)(hp + q*4);
    #pragma unroll
    for (int j = 0; j < 4; ++j) h[q*4 + j] = v[j];
  }
  float Dd = Dp[d];

  size_t base = (size_t)b * SEQ * D_INNER + (size_t)c * CH * D_INNER + d;
  const float* Br = Bbuf + ((size_t)b * SEQ + (size_t)c * CH) * 16;
  const float* Cr = Cbuf + ((size_t)b * SEQ + (size_t)c * CH) * 16;

  float Bc[16], Cc[16];
  #pragma unroll
  for (int s = 0; s < 16; ++s){ Bc[s] = Br[s]; Cc[s] = Cr[s]; }
  float xn = b2f(xconv[base]);
  float gn = b2f(gate[base]);

  for (int l = 0; l < CH; ++l){
    float x = xn, g = gn;
    float Bl[16], Cl[16];
    #pragma unroll
    for (int s = 0; s < 16; ++s){ Bl[s] = Bc[s]; Cl[s] = Cc[s]; }
    if (l < CH-1){
      size_t idx = base + (size_t)(l+1)*D_INNER;
      xn = b2f(xconv[idx]); gn = b2f(gate[idx]);
      #pragma unroll
      for (int s = 0; s < 16; ++s){ Bc[s] = Br[(l+1)*16 + s]; Cc[s] = Cr[(l+1)*16 + s]; }
    }
    float ya[4] = {0.f, 0.f, 0.f, 0.f};
    #pragma unroll
    for (int s = 0; s < 16; ++s){
      float hv = Abar[s]*h[s] + x*Bl[s];
      h[s] = hv;
      ya[s & 3] += hv * Cl[s];
    }
    float y = ((ya[0]+ya[1]) + (ya[2]+ya[3]) + Dd*x) * g;
    ybuf[base + (size_t)l*D_INNER] = f2b(y);
  }
}

extern "C" void kernel_launch(void* const* d_in, const int* in_sizes, int n_in,
                              void* d_out, int out_size, void* d_ws, size_t ws_size,
                              hipStream_t stream){
  const float* x      = (const float*)d_in[0];
  const float* B_mod  = (const float*)d_in[1];
  const float* C_mod  = (const float*)d_in[2];
  const float* W_in   = (const float*)d_in[3];
  const float* b_in   = (const float*)d_in[4];
  const float* conv_w = (const float*)d_in[5];
  const float* conv_b = (const float*)d_in[6];
  const float* A_log  = (const float*)d_in[7];
  const float* Dp     = (const float*)d_in[8];
  const float* W_B    = (const float*)d_in[9];
  const float* b_B    = (const float*)d_in[10];
  const float* W_C    = (const float*)d_in[11];
  const float* b_C    = (const float*)d_in[12];
  const float* W_out  = (const float*)d_in[13];
  const float* b_out  = (const float*)d_in[14];
  float* out = (float*)d_out;   // reference output dtype is float32

  char* ws = (char*)d_ws;
  size_t off = 0;
  auto alloc = [&](size_t bytes)->char* {
    char* p = ws + off; off += (bytes + 255) & ~(size_t)255; return p;
  };
  u16* Wt_in  = (u16*)alloc((size_t)(2*D_INNER)*D_MODEL*2); // 8.39 MB; dead after gemm1
  u16* Wt_out = (u16*)alloc((size_t)D_MODEL*D_INNER*2);     // 4.2 MB
  u16* xs     = (u16*)alloc((size_t)ML*D_INNER*2);          // x_ssm_silu; reused as y
  u16* gatep  = (u16*)alloc((size_t)ML*D_INNER*2);          // silu(x_res)
  u16* xconv  = (u16*)alloc((size_t)ML*D_INNER*2);
  float* Bbuf = (float*)alloc((size_t)ML*D_STATE*4);
  float* Cbuf = (float*)alloc((size_t)ML*D_STATE*4);
  u16* xbf    = (u16*)alloc((size_t)ML*D_MODEL*2);          // 16.8 MB; dead after gemm1
  float* hin  = (float*)alloc((size_t)BATCH*NCHUNK*D_INNER*16*4);
  u16* Wt_bc  = (u16*)alloc((size_t)32*D_INNER*2);          // 131 KB
  float* hend    = (float*)xbf;    // reuse: xbf dead before state_k (16.78 MB fits)
  float* partial = (float*)Wt_in;  // reuse: Wt_in dead after gemm1 (KSEG*ML*32*4 = 8.39 MB, exact)
  u16* ybuf = xs;                  // xs dead after conv/bc_gemm

  transpose_cast_k<<<dim3((2*D_INNER)/32, D_MODEL/32), 256, 0, stream>>>(W_in, Wt_in, D_MODEL, 2*D_INNER);
  transpose_cast_k<<<dim3(D_MODEL/32, D_INNER/32),     256, 0, stream>>>(W_out, Wt_out, D_INNER, D_MODEL);
  cast_k<<<dim3((ML*D_MODEL)/(256*8)), 256, 0, stream>>>(x, xbf);
  bc_wt_k<<<dim3(D_INNER/256, 32), 256, 0, stream>>>(W_B, W_C, Wt_bc);

  gemm_bt<1,0><<<dim3((2*D_INNER)/128, ML/128), 256, 0, stream>>>(
      (const void*)xbf, Wt_in, b_in, xs, gatep, nullptr, ML, 2*D_INNER, D_MODEL);

  conv_k<<<dim3(ML), 256, 0, stream>>>(xs, conv_w, conv_b, xconv);

  bc_gemm_k<<<dim3(KSEG, ML/128), 256, 0, stream>>>(xconv, Wt_bc, partial);
  bc_reduce_k<<<dim3((ML*32)/256), 256, 0, stream>>>(
      partial, b_B, B_mod, b_C, C_mod, Bbuf, Cbuf);

  state_k<<<dim3(NCHUNK, D_INNER/256, BATCH), 256, 0, stream>>>(xconv, Bbuf, A_log, hend);
  prefix_k<<<dim3((BATCH*D_INNER*16)/256), 256, 0, stream>>>(hend, A_log, hin);
  scan2_k<<<dim3(NCHUNK, D_INNER/256, BATCH), 256, 0, stream>>>(
      xconv, gatep, Bbuf, Cbuf, A_log, Dp, hin, ybuf);

  gemm_bt<0,0><<<dim3(D_MODEL/128, ML/128), 256, 0, stream>>>(
      (const void*)ybuf, Wt_out, b_out, nullptr, nullptr, out, ML, D_MODEL, D_INNER);
}

// Round 6
// 400.764 us; speedup vs baseline: 3.9991x; 1.0076x over previous
//
#include <hip/hip_runtime.h>
#include <stdint.h>

#define D_MODEL 1024
#define D_STATE 16
#define D_INNER 2048
#define BATCH   4
#define SEQ     2048
#define ML      (BATCH*SEQ)   // 8192 rows
#define CH      64
#define NCHUNK  (SEQ/CH)      // 32
#define KSEG    8             // K-split for B/C projection GEMM

typedef unsigned short u16;
typedef u16   u16x8  __attribute__((ext_vector_type(8)));
typedef short s16x8  __attribute__((ext_vector_type(8)));
typedef float f32x4  __attribute__((ext_vector_type(4)));

__device__ __forceinline__ float b2f(u16 u){
  union { uint32_t i; float f; } v; v.i = ((uint32_t)u) << 16; return v.f;
}
__device__ __forceinline__ u16 f2b(float f){
  uint32_t x = __float_as_uint(f);
  return (u16)((x + 0x7fffu + ((x >> 16) & 1u)) >> 16);   // RNE
}
__device__ __forceinline__ float silu_f(float v){
  return v / (1.f + __expf(-v));
}
// async global->LDS, 16 B per lane; lds base must be wave-uniform (lane i lands at base + i*16)
__device__ __forceinline__ void gl_lds16(const void* gp, void* lp){
  __builtin_amdgcn_global_load_lds(
      (const __attribute__((address_space(1))) void*)gp,
      (__attribute__((address_space(3))) void*)lp, 16, 0, 0);
}

// ------------- transpose + cast: in f32 (R x C) -> out bf16 (C x R) -------------
__global__ __launch_bounds__(256) void transpose_cast_k(const float* __restrict__ in,
                                                        u16* __restrict__ out,
                                                        int R, int C){
  __shared__ float tile[32][33];
  int bx = blockIdx.x * 32, by = blockIdx.y * 32;
  int tx = threadIdx.x & 31, ty = threadIdx.x >> 5;
  #pragma unroll
  for (int i = 0; i < 32; i += 8)
    tile[ty + i][tx] = in[(size_t)(by + ty + i) * C + bx + tx];
  __syncthreads();
  #pragma unroll
  for (int i = 0; i < 32; i += 8)
    out[(size_t)(bx + ty + i) * R + by + tx] = f2b(tile[tx][ty + i]);
}

// ------------- elementwise cast f32 -> bf16 (8 per thread) -------------
__global__ __launch_bounds__(256) void cast_k(const float* __restrict__ in,
                                              u16* __restrict__ out){
  size_t i = ((size_t)blockIdx.x * 256 + threadIdx.x) * 8;
  f32x4 a = *(const f32x4*)(in + i);
  f32x4 b = *(const f32x4*)(in + i + 4);
  u16x8 o;
  #pragma unroll
  for (int j = 0; j < 4; ++j){ o[j] = f2b(a[j]); o[4+j] = f2b(b[j]); }
  *(u16x8*)(out + i) = o;
}

// ------------- W_B|W_C (2048x16 f32 each) -> Wt_bc bf16 32x2048 -------------
__global__ __launch_bounds__(256) void bc_wt_k(const float* __restrict__ W_B,
                                               const float* __restrict__ W_C,
                                               u16* __restrict__ Wt){
  int n = blockIdx.y;                          // 0..31
  int k = blockIdx.x * 256 + threadIdx.x;      // 0..2047
  const float* src = (n < 16) ? W_B : W_C;
  Wt[(size_t)n * D_INNER + k] = f2b(src[(size_t)k * 16 + (n & 15)]);
}

// ------------- MFMA GEMM (m97 structure): D = A(MxK) * Bt(NxK)^T -------------
// Staging via global_load_lds width=16; LDS tiles unpadded 128x32 u16.
// MODE 0: outf[row*N+col] = f32(acc + bias[col])          (final output, f32)
// MODE 1: s = silu(acc + bias[col]); col<N/2 -> out0 bf16 (x_ssm), else out1 bf16 (gate)
template<int MODE>
__global__ __launch_bounds__(256) void gemm_bt(const u16* __restrict__ A,
                                               const u16* __restrict__ Bt,
                                               const float* __restrict__ bias,
                                               u16* __restrict__ out0,
                                               u16* __restrict__ out1,
                                               float* __restrict__ outf,
                                               int M, int N, int K){
  __shared__ __align__(16) u16 Asb[128*32];   // unpadded: DMA layout constraint
  __shared__ __align__(16) u16 Bsb[128*32];
  const int t    = threadIdx.x;
  const int n0   = blockIdx.x * 128;
  const int m0   = blockIdx.y * 128;
  const int wave = t >> 6, lane = t & 63;
  const int wm   = (wave >> 1) * 64, wn = (wave & 1) * 64;
  const int lrow = lane & 15, kq = (lane >> 4) * 8;
  const int srow = lane >> 2;            // staging: row within 16-row block
  const int scol = (lane & 3) * 8;       // staging: 8-u16 chunk within row

  f32x4 acc[4][4];
  #pragma unroll
  for (int i = 0; i < 4; ++i)
    #pragma unroll
    for (int j = 0; j < 4; ++j)
      acc[i][j] = (f32x4){0.f, 0.f, 0.f, 0.f};

  for (int k0 = 0; k0 < K; k0 += 32) {
    // each wave DMAs 2 16-row blocks of A and 2 of B (1024 B per instruction)
    #pragma unroll
    for (int i = 0; i < 2; ++i) {
      int R0 = (wave*2 + i) * 16;        // 0,16,...,112
      gl_lds16(&A [(size_t)(m0 + R0 + srow)*K + k0 + scol], &Asb[R0*32]);
      gl_lds16(&Bt[(size_t)(n0 + R0 + srow)*K + k0 + scol], &Bsb[R0*32]);
    }
    __syncthreads();
    s16x8 af[4], bfr[4];
    #pragma unroll
    for (int i = 0; i < 4; ++i) af[i]  = *(const s16x8*)&Asb[(wm + i*16 + lrow)*32 + kq];
    #pragma unroll
    for (int j = 0; j < 4; ++j) bfr[j] = *(const s16x8*)&Bsb[(wn + j*16 + lrow)*32 + kq];
    #pragma unroll
    for (int i = 0; i < 4; ++i)
      #pragma unroll
      for (int j = 0; j < 4; ++j)
        acc[i][j] = __builtin_amdgcn_mfma_f32_16x16x32_bf16(af[i], bfr[j], acc[i][j], 0, 0, 0);
    __syncthreads();
  }

  const int Nh = N >> 1;
  #pragma unroll
  for (int i = 0; i < 4; ++i) {
    #pragma unroll
    for (int j = 0; j < 4; ++j) {
      int col = n0 + wn + j*16 + lrow;
      float bv = bias[col];
      #pragma unroll
      for (int r = 0; r < 4; ++r) {
        int row = m0 + wm + i*16 + (lane >> 4)*4 + r;   // C/D: col=lane&15, row=quad*4+reg
        float v = acc[i][j][r] + bv;
        if (MODE == 0) {
          outf[(size_t)row * N + col] = v;
        } else {
          float s = silu_f(v);
          if (col < Nh) out0[(size_t)row * Nh + col]        = f2b(s);
          else          out1[(size_t)row * Nh + (col - Nh)] = f2b(s);
        }
      }
    }
  }
}

// ------------- depthwise conv(3) only -------------
__global__ __launch_bounds__(256) void conv_k(const u16* __restrict__ xs,
    const float* __restrict__ conv_w, const float* __restrict__ conv_b,
    u16* __restrict__ xconv){
  int bl = blockIdx.x;
  int l = bl & (SEQ-1);
  int d = threadIdx.x * 8;
  const u16* row0 = xs + (size_t)bl * D_INNER + d;

  float f0[8], fm[8], fp[8];
  { u16x8 v = *(const u16x8*)row0;
    #pragma unroll
    for (int j = 0; j < 8; ++j) f0[j] = b2f(v[j]); }
  if (l > 0) {
    u16x8 v = *(const u16x8*)(row0 - D_INNER);
    #pragma unroll
    for (int j = 0; j < 8; ++j) fm[j] = b2f(v[j]);
  } else {
    #pragma unroll
    for (int j = 0; j < 8; ++j) fm[j] = 0.f;
  }
  if (l < SEQ-1) {
    u16x8 v = *(const u16x8*)(row0 + D_INNER);
    #pragma unroll
    for (int j = 0; j < 8; ++j) fp[j] = b2f(v[j]);
  } else {
    #pragma unroll
    for (int j = 0; j < 8; ++j) fp[j] = 0.f;
  }

  const float* wp = conv_w + (size_t)d * 3;
  float wl[24];
  #pragma unroll
  for (int q = 0; q < 6; ++q){
    f32x4 v = *(const f32x4*)(wp + q*4);
    #pragma unroll
    for (int j = 0; j < 4; ++j) wl[q*4 + j] = v[j];
  }
  float cb[8];
  { f32x4 c0 = *(const f32x4*)(conv_b + d), c1 = *(const f32x4*)(conv_b + d + 4);
    #pragma unroll
    for (int j = 0; j < 4; ++j){ cb[j] = c0[j]; cb[4+j] = c1[j]; } }

  u16x8 o;
  #pragma unroll
  for (int j = 0; j < 8; ++j)
    o[j] = f2b(wl[3*j]*fm[j] + wl[3*j+1]*f0[j] + wl[3*j+2]*fp[j] + cb[j]);
  *(u16x8*)(xconv + (size_t)bl * D_INNER + d) = o;
}

// ------------- B/C projection GEMM: xconv(8192x2048) @ Wt_bc^T(32x2048) ------
__global__ __launch_bounds__(256) void bc_gemm_k(const u16* __restrict__ xconv,
                                                 const u16* __restrict__ Wt,
                                                 float* __restrict__ partial){
  __shared__ __align__(16) u16 Asb[128*40];
  __shared__ __align__(16) u16 Wsb[32*40];
  const int kseg = blockIdx.x;
  const int m0   = blockIdx.y * 128;
  const int t    = threadIdx.x;
  const int wave = t >> 6, lane = t & 63;
  const int wm   = wave * 32;
  const int lrow = lane & 15, kq = (lane >> 4) * 8;

  f32x4 acc[2][2];
  #pragma unroll
  for (int i = 0; i < 2; ++i)
    #pragma unroll
    for (int j = 0; j < 2; ++j)
      acc[i][j] = (f32x4){0.f, 0.f, 0.f, 0.f};

  const int kbase = kseg * (D_INNER / KSEG);
  for (int ks = 0; ks < (D_INNER / KSEG); ks += 32) {
    int k0 = kbase + ks;
    #pragma unroll
    for (int i = 0; i < 2; ++i) {
      int f = (i*256 + t) * 8;
      int r = f >> 5, c = f & 31;
      *(u16x8*)&Asb[r*40 + c] = *(const u16x8*)&xconv[(size_t)(m0 + r)*D_INNER + k0 + c];
    }
    if (t < 128) {
      int f = t * 8;
      int r = f >> 5, c = f & 31;
      *(u16x8*)&Wsb[r*40 + c] = *(const u16x8*)&Wt[(size_t)r*D_INNER + k0 + c];
    }
    __syncthreads();
    s16x8 af[2], wf[2];
    #pragma unroll
    for (int i = 0; i < 2; ++i) af[i] = *(const s16x8*)&Asb[(wm + i*16 + lrow)*40 + kq];
    #pragma unroll
    for (int j = 0; j < 2; ++j) wf[j] = *(const s16x8*)&Wsb[(j*16 + lrow)*40 + kq];
    #pragma unroll
    for (int i = 0; i < 2; ++i)
      #pragma unroll
      for (int j = 0; j < 2; ++j)
        acc[i][j] = __builtin_amdgcn_mfma_f32_16x16x32_bf16(af[i], wf[j], acc[i][j], 0, 0, 0);
    __syncthreads();
  }

  #pragma unroll
  for (int i = 0; i < 2; ++i)
    #pragma unroll
    for (int j = 0; j < 2; ++j)
      #pragma unroll
      for (int r = 0; r < 4; ++r) {
        int row = m0 + wm + i*16 + (lane >> 4)*4 + r;
        int col = j*16 + lrow;
        partial[((size_t)kseg * ML + row) * 32 + col] = acc[i][j][r];
      }
}

// ------------- reduce partials + bias + mod -> Bbuf/Cbuf -------------
__global__ __launch_bounds__(256) void bc_reduce_k(const float* __restrict__ partial,
    const float* __restrict__ b_B, const float* __restrict__ B_mod,
    const float* __restrict__ b_C, const float* __restrict__ C_mod,
    float* __restrict__ Bbuf, float* __restrict__ Cbuf){
  int g = blockIdx.x * 256 + threadIdx.x;   // < ML*32
  int row = g >> 5, col = g & 31;
  int b = row >> 11;
  float s = 0.f;
  #pragma unroll
  for (int seg = 0; seg < KSEG; ++seg)
    s += partial[(size_t)seg * ML * 32 + g];
  if (col < 16) Bbuf[(size_t)row*16 + col]      = s + b_B[col]      + B_mod[b*16 + col];
  else          Cbuf[(size_t)row*16 + col - 16] = s + b_C[col - 16] + C_mod[b*16 + col - 16];
}

// ------------- chunked scan, pass 1: local chunk-final states -------------
__global__ __launch_bounds__(256) void state_k(const u16* __restrict__ xconv,
    const float* __restrict__ Bbuf, const float* __restrict__ A_log,
    float* __restrict__ hend){
  int c = blockIdx.x, db = blockIdx.y, b = blockIdx.z;
  int d = db*256 + threadIdx.x;

  float Abar[16];
  #pragma unroll
  for (int s = 0; s < 16; ++s)
    Abar[s] = __expf(-0.1f * __expf(A_log[d*16 + s]));
  float h[16];
  #pragma unroll
  for (int s = 0; s < 16; ++s) h[s] = 0.f;

  size_t base = (size_t)b * SEQ * D_INNER + (size_t)c * CH * D_INNER + d;
  const float* Br = Bbuf + ((size_t)b * SEQ + (size_t)c * CH) * 16;

  float Bc[16];
  #pragma unroll
  for (int s = 0; s < 16; ++s) Bc[s] = Br[s];
  float xn = b2f(xconv[base]);

  for (int l = 0; l < CH; ++l){
    float x = xn;
    float Bl[16];
    #pragma unroll
    for (int s = 0; s < 16; ++s) Bl[s] = Bc[s];
    if (l < CH-1){
      xn = b2f(xconv[base + (size_t)(l+1)*D_INNER]);
      #pragma unroll
      for (int s = 0; s < 16; ++s) Bc[s] = Br[(l+1)*16 + s];
    }
    #pragma unroll
    for (int s = 0; s < 16; ++s)
      h[s] = Abar[s]*h[s] + x*Bl[s];
  }
  float* hp = hend + (((size_t)(b*NCHUNK + c))*D_INNER + d)*16;
  #pragma unroll
  for (int q = 0; q < 4; ++q)
    *(f32x4*)(hp + q*4) = (f32x4){h[q*4], h[q*4+1], h[q*4+2], h[q*4+3]};
}

// ------------- chunked scan, pass 2: prefix across chunks -------------
__global__ __launch_bounds__(256) void prefix_k(const float* __restrict__ hend,
    const float* __restrict__ A_log, float* __restrict__ hin){
  int g = blockIdx.x*256 + threadIdx.x;
  int s = g & 15;
  int d = (g >> 4) & (D_INNER-1);
  int b = g >> 15;
  float decay = __expf(-0.1f * (float)CH * __expf(A_log[d*16 + s]));
  size_t stride = (size_t)D_INNER * 16;
  const float* he = hend + (size_t)b*NCHUNK*stride + (size_t)d*16 + s;
  float*       hi = hin  + (size_t)b*NCHUNK*stride + (size_t)d*16 + s;
  float h = 0.f;
  for (int c0 = 0; c0 < NCHUNK; c0 += 8){
    float v[8];
    #pragma unroll
    for (int i = 0; i < 8; ++i) v[i] = he[(size_t)(c0+i)*stride];
    #pragma unroll
    for (int i = 0; i < 8; ++i){
      hi[(size_t)(c0+i)*stride] = h;
      h = decay*h + v[i];
    }
  }
}

// ------------- chunked scan, pass 3: full scan per chunk from hin -------------
__global__ __launch_bounds__(256) void scan2_k(const u16* __restrict__ xconv,
    const u16* __restrict__ gate, const float* __restrict__ Bbuf, const float* __restrict__ Cbuf,
    const float* __restrict__ A_log, const float* __restrict__ Dp,
    const float* __restrict__ hin, u16* __restrict__ ybuf){
  int c = blockIdx.x, db = blockIdx.y, b = blockIdx.z;
  int d = db*256 + threadIdx.x;

  float Abar[16];
  #pragma unroll
  for (int s = 0; s < 16; ++s)
    Abar[s] = __expf(-0.1f * __expf(A_log[d*16 + s]));
  float h[16];
  const float* hp = hin + (((size_t)(b*NCHUNK + c))*D_INNER + d)*16;
  #pragma unroll
  for (int q = 0; q < 4; ++q){
    f32x4 v = *(const f32x4*)(hp + q*4);
    #pragma unroll
    for (int j = 0; j < 4; ++j) h[q*4 + j] = v[j];
  }
  float Dd = Dp[d];

  size_t base = (size_t)b * SEQ * D_INNER + (size_t)c * CH * D_INNER + d;
  const float* Br = Bbuf + ((size_t)b * SEQ + (size_t)c * CH) * 16;
  const float* Cr = Cbuf + ((size_t)b * SEQ + (size_t)c * CH) * 16;

  float Bc[16], Cc[16];
  #pragma unroll
  for (int s = 0; s < 16; ++s){ Bc[s] = Br[s]; Cc[s] = Cr[s]; }
  float xn = b2f(xconv[base]);
  float gn = b2f(gate[base]);

  for (int l = 0; l < CH; ++l){
    float x = xn, g = gn;
    float Bl[16], Cl[16];
    #pragma unroll
    for (int s = 0; s < 16; ++s){ Bl[s] = Bc[s]; Cl[s] = Cc[s]; }
    if (l < CH-1){
      size_t idx = base + (size_t)(l+1)*D_INNER;
      xn = b2f(xconv[idx]); gn = b2f(gate[idx]);
      #pragma unroll
      for (int s = 0; s < 16; ++s){ Bc[s] = Br[(l+1)*16 + s]; Cc[s] = Cr[(l+1)*16 + s]; }
    }
    float ya[4] = {0.f, 0.f, 0.f, 0.f};
    #pragma unroll
    for (int s = 0; s < 16; ++s){
      float hv = Abar[s]*h[s] + x*Bl[s];
      h[s] = hv;
      ya[s & 3] += hv * Cl[s];
    }
    float y = ((ya[0]+ya[1]) + (ya[2]+ya[3]) + Dd*x) * g;
    ybuf[base + (size_t)l*D_INNER] = f2b(y);
  }
}

extern "C" void kernel_launch(void* const* d_in, const int* in_sizes, int n_in,
                              void* d_out, int out_size, void* d_ws, size_t ws_size,
                              hipStream_t stream){
  const float* x      = (const float*)d_in[0];
  const float* B_mod  = (const float*)d_in[1];
  const float* C_mod  = (const float*)d_in[2];
  const float* W_in   = (const float*)d_in[3];
  const float* b_in   = (const float*)d_in[4];
  const float* conv_w = (const float*)d_in[5];
  const float* conv_b = (const float*)d_in[6];
  const float* A_log  = (const float*)d_in[7];
  const float* Dp     = (const float*)d_in[8];
  const float* W_B    = (const float*)d_in[9];
  const float* b_B    = (const float*)d_in[10];
  const float* W_C    = (const float*)d_in[11];
  const float* b_C    = (const float*)d_in[12];
  const float* W_out  = (const float*)d_in[13];
  const float* b_out  = (const float*)d_in[14];
  float* out = (float*)d_out;   // reference output dtype is float32

  char* ws = (char*)d_ws;
  size_t off = 0;
  auto alloc = [&](size_t bytes)->char* {
    char* p = ws + off; off += (bytes + 255) & ~(size_t)255; return p;
  };
  u16* Wt_in  = (u16*)alloc((size_t)(2*D_INNER)*D_MODEL*2); // 8.39 MB; dead after gemm1
  u16* Wt_out = (u16*)alloc((size_t)D_MODEL*D_INNER*2);     // 4.2 MB
  u16* xs     = (u16*)alloc((size_t)ML*D_INNER*2);          // x_ssm_silu; reused as y
  u16* gatep  = (u16*)alloc((size_t)ML*D_INNER*2);          // silu(x_res)
  u16* xconv  = (u16*)alloc((size_t)ML*D_INNER*2);
  float* Bbuf = (float*)alloc((size_t)ML*D_STATE*4);
  float* Cbuf = (float*)alloc((size_t)ML*D_STATE*4);
  u16* xbf    = (u16*)alloc((size_t)ML*D_MODEL*2);          // 16.8 MB; dead after gemm1
  float* hin  = (float*)alloc((size_t)BATCH*NCHUNK*D_INNER*16*4);
  u16* Wt_bc  = (u16*)alloc((size_t)32*D_INNER*2);          // 131 KB
  float* hend    = (float*)xbf;    // reuse: xbf dead before state_k
  float* partial = (float*)Wt_in;  // reuse: Wt_in dead after gemm1 (8.39 MB, exact)
  u16* ybuf = xs;                  // xs dead after conv/bc_gemm

  transpose_cast_k<<<dim3((2*D_INNER)/32, D_MODEL/32), 256, 0, stream>>>(W_in, Wt_in, D_MODEL, 2*D_INNER);
  transpose_cast_k<<<dim3(D_MODEL/32, D_INNER/32),     256, 0, stream>>>(W_out, Wt_out, D_INNER, D_MODEL);
  cast_k<<<dim3((ML*D_MODEL)/(256*8)), 256, 0, stream>>>(x, xbf);
  bc_wt_k<<<dim3(D_INNER/256, 32), 256, 0, stream>>>(W_B, W_C, Wt_bc);

  gemm_bt<1><<<dim3((2*D_INNER)/128, ML/128), 256, 0, stream>>>(
      xbf, Wt_in, b_in, xs, gatep, nullptr, ML, 2*D_INNER, D_MODEL);

  conv_k<<<dim3(ML), 256, 0, stream>>>(xs, conv_w, conv_b, xconv);

  bc_gemm_k<<<dim3(KSEG, ML/128), 256, 0, stream>>>(xconv, Wt_bc, partial);
  bc_reduce_k<<<dim3((ML*32)/256), 256, 0, stream>>>(
      partial, b_B, B_mod, b_C, C_mod, Bbuf, Cbuf);

  state_k<<<dim3(NCHUNK, D_INNER/256, BATCH), 256, 0, stream>>>(xconv, Bbuf, A_log, hend);
  prefix_k<<<dim3((BATCH*D_INNER*16)/256), 256, 0, stream>>>(hend, A_log, hin);
  scan2_k<<<dim3(NCHUNK, D_INNER/256, BATCH), 256, 0, stream>>>(
      xconv, gatep, Bbuf, Cbuf, A_log, Dp, hin, ybuf);

  gemm_bt<0><<<dim3(D_MODEL/128, ML/128), 256, 0, stream>>>(
      ybuf, Wt_out, b_out, nullptr, nullptr, out, ML, D_MODEL, D_INNER);
}

// Round 7
// 387.259 us; speedup vs baseline: 4.1385x; 1.0349x over previous
//
#include <hip/hip_runtime.h>
#include <stdint.h>

#define D_MODEL 1024
#define D_STATE 16
#define D_INNER 2048
#define BATCH   4
#define SEQ     2048
#define ML      (BATCH*SEQ)   // 8192 rows
#define CH      64
#define NCHUNK  (SEQ/CH)      // 32
#define KSEG    8             // K-split for B/C projection GEMM

typedef unsigned short u16;
typedef u16   u16x8  __attribute__((ext_vector_type(8)));
typedef short s16x8  __attribute__((ext_vector_type(8)));
typedef float f32x4  __attribute__((ext_vector_type(4)));

__device__ __forceinline__ float b2f(u16 u){
  union { uint32_t i; float f; } v; v.i = ((uint32_t)u) << 16; return v.f;
}
__device__ __forceinline__ u16 f2b(float f){
  uint32_t x = __float_as_uint(f);
  return (u16)((x + 0x7fffu + ((x >> 16) & 1u)) >> 16);   // RNE
}
__device__ __forceinline__ float silu_f(float v){
  return v / (1.f + __expf(-v));
}
// async global->LDS, 16 B per lane; lds base must be wave-uniform (lane i lands at base + i*16)
__device__ __forceinline__ void gl_lds16(const void* gp, void* lp){
  __builtin_amdgcn_global_load_lds(
      (const __attribute__((address_space(1))) void*)gp,
      (__attribute__((address_space(3))) void*)lp, 16, 0, 0);
}

// ------------- transpose + cast: in f32 (R x C) -> out bf16 (C x R) -------------
__global__ __launch_bounds__(256) void transpose_cast_k(const float* __restrict__ in,
                                                        u16* __restrict__ out,
                                                        int R, int C){
  __shared__ float tile[32][33];
  int bx = blockIdx.x * 32, by = blockIdx.y * 32;
  int tx = threadIdx.x & 31, ty = threadIdx.x >> 5;
  #pragma unroll
  for (int i = 0; i < 32; i += 8)
    tile[ty + i][tx] = in[(size_t)(by + ty + i) * C + bx + tx];
  __syncthreads();
  #pragma unroll
  for (int i = 0; i < 32; i += 8)
    out[(size_t)(bx + ty + i) * R + by + tx] = f2b(tile[tx][ty + i]);
}

// ------------- elementwise cast f32 -> bf16 (8 per thread) -------------
__global__ __launch_bounds__(256) void cast_k(const float* __restrict__ in,
                                              u16* __restrict__ out){
  size_t i = ((size_t)blockIdx.x * 256 + threadIdx.x) * 8;
  f32x4 a = *(const f32x4*)(in + i);
  f32x4 b = *(const f32x4*)(in + i + 4);
  u16x8 o;
  #pragma unroll
  for (int j = 0; j < 4; ++j){ o[j] = f2b(a[j]); o[4+j] = f2b(b[j]); }
  *(u16x8*)(out + i) = o;
}

// ------------- W_B|W_C (2048x16 f32 each) -> Wt_bc bf16 32x2048 -------------
__global__ __launch_bounds__(256) void bc_wt_k(const float* __restrict__ W_B,
                                               const float* __restrict__ W_C,
                                               u16* __restrict__ Wt){
  int n = blockIdx.y;                          // 0..31
  int k = blockIdx.x * 256 + threadIdx.x;      // 0..2047
  const float* src = (n < 16) ? W_B : W_C;
  Wt[(size_t)n * D_INNER + k] = f2b(src[(size_t)k * 16 + (n & 15)]);
}

// ------------- MFMA GEMM, double-buffered DMA, 1 barrier/iter -------------
// 1-D grid, XCD swizzle: bid&7 selects the n-column group (B stays L2-resident/XCD).
// MODE 0: outf[row*N+col] = f32(acc + bias[col])          (final output, f32)
// MODE 1: s = silu(acc + bias[col]); col<N/2 -> out0 bf16 (x_ssm), else out1 bf16 (gate)
template<int MODE>
__global__ __launch_bounds__(256) void gemm_bt(const u16* __restrict__ A,
                                               const u16* __restrict__ Bt,
                                               const float* __restrict__ bias,
                                               u16* __restrict__ out0,
                                               u16* __restrict__ out1,
                                               float* __restrict__ outf,
                                               int M, int N, int K, int n_per_xcd){
  __shared__ __align__(16) u16 Asb[2][128*32];   // unpadded: DMA layout constraint
  __shared__ __align__(16) u16 Bsb[2][128*32];
  const int bid = blockIdx.x;
  const int xcd = bid & 7, t2 = bid >> 3;
  const int n0 = (xcd * n_per_xcd + (t2 % n_per_xcd)) * 128;
  const int m0 = (t2 / n_per_xcd) * 128;
  const int t    = threadIdx.x;
  const int wave = t >> 6, lane = t & 63;
  const int wm   = (wave >> 1) * 64, wn = (wave & 1) * 64;
  const int lrow = lane & 15, kq = (lane >> 4) * 8;
  const int srow = lane >> 2;            // staging: row within 16-row block
  const int scol = (lane & 3) * 8;       // staging: 8-u16 chunk within row

  f32x4 acc[4][4];
  #pragma unroll
  for (int i = 0; i < 4; ++i)
    #pragma unroll
    for (int j = 0; j < 4; ++j)
      acc[i][j] = (f32x4){0.f, 0.f, 0.f, 0.f};

  auto stage = [&](int buf, int k0){
    #pragma unroll
    for (int i = 0; i < 2; ++i) {
      int R0 = (wave*2 + i) * 16;        // 0,16,...,112
      gl_lds16(&A [(size_t)(m0 + R0 + srow)*K + k0 + scol], &Asb[buf][R0*32]);
      gl_lds16(&Bt[(size_t)(n0 + R0 + srow)*K + k0 + scol], &Bsb[buf][R0*32]);
    }
  };

  const int KT = K >> 5;
  stage(0, 0);
  __syncthreads();
  for (int kt = 0; kt < KT; ++kt) {
    const int cur = kt & 1;
    if (kt + 1 < KT) stage(1 - cur, (kt + 1) * 32);   // prefetch overlaps compute below
    s16x8 af[4], bfr[4];
    #pragma unroll
    for (int i = 0; i < 4; ++i) af[i]  = *(const s16x8*)&Asb[cur][(wm + i*16 + lrow)*32 + kq];
    #pragma unroll
    for (int j = 0; j < 4; ++j) bfr[j] = *(const s16x8*)&Bsb[cur][(wn + j*16 + lrow)*32 + kq];
    #pragma unroll
    for (int i = 0; i < 4; ++i)
      #pragma unroll
      for (int j = 0; j < 4; ++j)
        acc[i][j] = __builtin_amdgcn_mfma_f32_16x16x32_bf16(af[i], bfr[j], acc[i][j], 0, 0, 0);
    __syncthreads();   // drains prefetch DMA + protects cur buffer reuse
  }

  const int Nh = N >> 1;
  #pragma unroll
  for (int i = 0; i < 4; ++i) {
    #pragma unroll
    for (int j = 0; j < 4; ++j) {
      int col = n0 + wn + j*16 + lrow;
      float bv = bias[col];
      #pragma unroll
      for (int r = 0; r < 4; ++r) {
        int row = m0 + wm + i*16 + (lane >> 4)*4 + r;   // C/D: col=lane&15, row=quad*4+reg
        float v = acc[i][j][r] + bv;
        if (MODE == 0) {
          outf[(size_t)row * N + col] = v;
        } else {
          float s = silu_f(v);
          if (col < Nh) out0[(size_t)row * Nh + col]        = f2b(s);
          else          out1[(size_t)row * Nh + (col - Nh)] = f2b(s);
        }
      }
    }
  }
}

// ------------- depthwise conv(3) only -------------
__global__ __launch_bounds__(256) void conv_k(const u16* __restrict__ xs,
    const float* __restrict__ conv_w, const float* __restrict__ conv_b,
    u16* __restrict__ xconv){
  int bl = blockIdx.x;
  int l = bl & (SEQ-1);
  int d = threadIdx.x * 8;
  const u16* row0 = xs + (size_t)bl * D_INNER + d;

  float f0[8], fm[8], fp[8];
  { u16x8 v = *(const u16x8*)row0;
    #pragma unroll
    for (int j = 0; j < 8; ++j) f0[j] = b2f(v[j]); }
  if (l > 0) {
    u16x8 v = *(const u16x8*)(row0 - D_INNER);
    #pragma unroll
    for (int j = 0; j < 8; ++j) fm[j] = b2f(v[j]);
  } else {
    #pragma unroll
    for (int j = 0; j < 8; ++j) fm[j] = 0.f;
  }
  if (l < SEQ-1) {
    u16x8 v = *(const u16x8*)(row0 + D_INNER);
    #pragma unroll
    for (int j = 0; j < 8; ++j) fp[j] = b2f(v[j]);
  } else {
    #pragma unroll
    for (int j = 0; j < 8; ++j) fp[j] = 0.f;
  }

  const float* wp = conv_w + (size_t)d * 3;
  float wl[24];
  #pragma unroll
  for (int q = 0; q < 6; ++q){
    f32x4 v = *(const f32x4*)(wp + q*4);
    #pragma unroll
    for (int j = 0; j < 4; ++j) wl[q*4 + j] = v[j];
  }
  float cb[8];
  { f32x4 c0 = *(const f32x4*)(conv_b + d), c1 = *(const f32x4*)(conv_b + d + 4);
    #pragma unroll
    for (int j = 0; j < 4; ++j){ cb[j] = c0[j]; cb[4+j] = c1[j]; } }

  u16x8 o;
  #pragma unroll
  for (int j = 0; j < 8; ++j)
    o[j] = f2b(wl[3*j]*fm[j] + wl[3*j+1]*f0[j] + wl[3*j+2]*fp[j] + cb[j]);
  *(u16x8*)(xconv + (size_t)bl * D_INNER + d) = o;
}

// ------------- B/C projection GEMM: xconv(8192x2048) @ Wt_bc^T(32x2048) ------
__global__ __launch_bounds__(256) void bc_gemm_k(const u16* __restrict__ xconv,
                                                 const u16* __restrict__ Wt,
                                                 float* __restrict__ partial){
  __shared__ __align__(16) u16 Asb[128*40];
  __shared__ __align__(16) u16 Wsb[32*40];
  const int kseg = blockIdx.x;
  const int m0   = blockIdx.y * 128;
  const int t    = threadIdx.x;
  const int wave = t >> 6, lane = t & 63;
  const int wm   = wave * 32;
  const int lrow = lane & 15, kq = (lane >> 4) * 8;

  f32x4 acc[2][2];
  #pragma unroll
  for (int i = 0; i < 2; ++i)
    #pragma unroll
    for (int j = 0; j < 2; ++j)
      acc[i][j] = (f32x4){0.f, 0.f, 0.f, 0.f};

  const int kbase = kseg * (D_INNER / KSEG);
  for (int ks = 0; ks < (D_INNER / KSEG); ks += 32) {
    int k0 = kbase + ks;
    #pragma unroll
    for (int i = 0; i < 2; ++i) {
      int f = (i*256 + t) * 8;
      int r = f >> 5, c = f & 31;
      *(u16x8*)&Asb[r*40 + c] = *(const u16x8*)&xconv[(size_t)(m0 + r)*D_INNER + k0 + c];
    }
    if (t < 128) {
      int f = t * 8;
      int r = f >> 5, c = f & 31;
      *(u16x8*)&Wsb[r*40 + c] = *(const u16x8*)&Wt[(size_t)r*D_INNER + k0 + c];
    }
    __syncthreads();
    s16x8 af[2], wf[2];
    #pragma unroll
    for (int i = 0; i < 2; ++i) af[i] = *(const s16x8*)&Asb[(wm + i*16 + lrow)*40 + kq];
    #pragma unroll
    for (int j = 0; j < 2; ++j) wf[j] = *(const s16x8*)&Wsb[(j*16 + lrow)*40 + kq];
    #pragma unroll
    for (int i = 0; i < 2; ++i)
      #pragma unroll
      for (int j = 0; j < 2; ++j)
        acc[i][j] = __builtin_amdgcn_mfma_f32_16x16x32_bf16(af[i], wf[j], acc[i][j], 0, 0, 0);
    __syncthreads();
  }

  #pragma unroll
  for (int i = 0; i < 2; ++i)
    #pragma unroll
    for (int j = 0; j < 2; ++j)
      #pragma unroll
      for (int r = 0; r < 4; ++r) {
        int row = m0 + wm + i*16 + (lane >> 4)*4 + r;
        int col = j*16 + lrow;
        partial[((size_t)kseg * ML + row) * 32 + col] = acc[i][j][r];
      }
}

// ------------- reduce partials + bias + mod -> Bbuf/Cbuf -------------
__global__ __launch_bounds__(256) void bc_reduce_k(const float* __restrict__ partial,
    const float* __restrict__ b_B, const float* __restrict__ B_mod,
    const float* __restrict__ b_C, const float* __restrict__ C_mod,
    float* __restrict__ Bbuf, float* __restrict__ Cbuf){
  int g = blockIdx.x * 256 + threadIdx.x;   // < ML*32
  int row = g >> 5, col = g & 31;
  int b = row >> 11;
  float s = 0.f;
  #pragma unroll
  for (int seg = 0; seg < KSEG; ++seg)
    s += partial[(size_t)seg * ML * 32 + g];
  if (col < 16) Bbuf[(size_t)row*16 + col]      = s + b_B[col]      + B_mod[b*16 + col];
  else          Cbuf[(size_t)row*16 + col - 16] = s + b_C[col - 16] + C_mod[b*16 + col - 16];
}

// ------------- chunked scan, pass 1: local chunk-final states -------------
__global__ __launch_bounds__(256) void state_k(const u16* __restrict__ xconv,
    const float* __restrict__ Bbuf, const float* __restrict__ A_log,
    float* __restrict__ hend){
  int c = blockIdx.x, db = blockIdx.y, b = blockIdx.z;
  int d = db*256 + threadIdx.x;

  float Abar[16];
  #pragma unroll
  for (int s = 0; s < 16; ++s)
    Abar[s] = __expf(-0.1f * __expf(A_log[d*16 + s]));
  float h[16];
  #pragma unroll
  for (int s = 0; s < 16; ++s) h[s] = 0.f;

  size_t base = (size_t)b * SEQ * D_INNER + (size_t)c * CH * D_INNER + d;
  const float* Br = Bbuf + ((size_t)b * SEQ + (size_t)c * CH) * 16;

  float Bc[16];
  #pragma unroll
  for (int s = 0; s < 16; ++s) Bc[s] = Br[s];
  float xn = b2f(xconv[base]);

  for (int l = 0; l < CH; ++l){
    float x = xn;
    float Bl[16];
    #pragma unroll
    for (int s = 0; s < 16; ++s) Bl[s] = Bc[s];
    if (l < CH-1){
      xn = b2f(xconv[base + (size_t)(l+1)*D_INNER]);
      #pragma unroll
      for (int s = 0; s < 16; ++s) Bc[s] = Br[(l+1)*16 + s];
    }
    #pragma unroll
    for (int s = 0; s < 16; ++s)
      h[s] = Abar[s]*h[s] + x*Bl[s];
  }
  float* hp = hend + (((size_t)(b*NCHUNK + c))*D_INNER + d)*16;
  #pragma unroll
  for (int q = 0; q < 4; ++q)
    *(f32x4*)(hp + q*4) = (f32x4){h[q*4], h[q*4+1], h[q*4+2], h[q*4+3]};
}

// ------------- chunked scan, pass 2: prefix across chunks -------------
__global__ __launch_bounds__(256) void prefix_k(const float* __restrict__ hend,
    const float* __restrict__ A_log, float* __restrict__ hin){
  int g = blockIdx.x*256 + threadIdx.x;
  int s = g & 15;
  int d = (g >> 4) & (D_INNER-1);
  int b = g >> 15;
  float decay = __expf(-0.1f * (float)CH * __expf(A_log[d*16 + s]));
  size_t stride = (size_t)D_INNER * 16;
  const float* he = hend + (size_t)b*NCHUNK*stride + (size_t)d*16 + s;
  float*       hi = hin  + (size_t)b*NCHUNK*stride + (size_t)d*16 + s;
  float h = 0.f;
  for (int c0 = 0; c0 < NCHUNK; c0 += 8){
    float v[8];
    #pragma unroll
    for (int i = 0; i < 8; ++i) v[i] = he[(size_t)(c0+i)*stride];
    #pragma unroll
    for (int i = 0; i < 8; ++i){
      hi[(size_t)(c0+i)*stride] = h;
      h = decay*h + v[i];
    }
  }
}

// ------------- chunked scan, pass 3: full scan per chunk from hin -------------
__global__ __launch_bounds__(256) void scan2_k(const u16* __restrict__ xconv,
    const u16* __restrict__ gate, const float* __restrict__ Bbuf, const float* __restrict__ Cbuf,
    const float* __restrict__ A_log, const float* __restrict__ Dp,
    const float* __restrict__ hin, u16* __restrict__ ybuf){
  int c = blockIdx.x, db = blockIdx.y, b = blockIdx.z;
  int d = db*256 + threadIdx.x;

  float Abar[16];
  #pragma unroll
  for (int s = 0; s < 16; ++s)
    Abar[s] = __expf(-0.1f * __expf(A_log[d*16 + s]));
  float h[16];
  const float* hp = hin + (((size_t)(b*NCHUNK + c))*D_INNER + d)*16;
  #pragma unroll
  for (int q = 0; q < 4; ++q){
    f32x4 v = *(const f32x4*)(hp + q*4);
    #pragma unroll
    for (int j = 0; j < 4; ++j) h[q*4 + j] = v[j];
  }
  float Dd = Dp[d];

  size_t base = (size_t)b * SEQ * D_INNER + (size_t)c * CH * D_INNER + d;
  const float* Br = Bbuf + ((size_t)b * SEQ + (size_t)c * CH) * 16;
  const float* Cr = Cbuf + ((size_t)b * SEQ + (size_t)c * CH) * 16;

  float Bc[16], Cc[16];
  #pragma unroll
  for (int s = 0; s < 16; ++s){ Bc[s] = Br[s]; Cc[s] = Cr[s]; }
  float xn = b2f(xconv[base]);
  float gn = b2f(gate[base]);

  for (int l = 0; l < CH; ++l){
    float x = xn, g = gn;
    float Bl[16], Cl[16];
    #pragma unroll
    for (int s = 0; s < 16; ++s){ Bl[s] = Bc[s]; Cl[s] = Cc[s]; }
    if (l < CH-1){
      size_t idx = base + (size_t)(l+1)*D_INNER;
      xn = b2f(xconv[idx]); gn = b2f(gate[idx]);
      #pragma unroll
      for (int s = 0; s < 16; ++s){ Bc[s] = Br[(l+1)*16 + s]; Cc[s] = Cr[(l+1)*16 + s]; }
    }
    float ya[4] = {0.f, 0.f, 0.f, 0.f};
    #pragma unroll
    for (int s = 0; s < 16; ++s){
      float hv = Abar[s]*h[s] + x*Bl[s];
      h[s] = hv;
      ya[s & 3] += hv * Cl[s];
    }
    float y = ((ya[0]+ya[1]) + (ya[2]+ya[3]) + Dd*x) * g;
    ybuf[base + (size_t)l*D_INNER] = f2b(y);
  }
}

extern "C" void kernel_launch(void* const* d_in, const int* in_sizes, int n_in,
                              void* d_out, int out_size, void* d_ws, size_t ws_size,
                              hipStream_t stream){
  const float* x      = (const float*)d_in[0];
  const float* B_mod  = (const float*)d_in[1];
  const float* C_mod  = (const float*)d_in[2];
  const float* W_in   = (const float*)d_in[3];
  const float* b_in   = (const float*)d_in[4];
  const float* conv_w = (const float*)d_in[5];
  const float* conv_b = (const float*)d_in[6];
  const float* A_log  = (const float*)d_in[7];
  const float* Dp     = (const float*)d_in[8];
  const float* W_B    = (const float*)d_in[9];
  const float* b_B    = (const float*)d_in[10];
  const float* W_C    = (const float*)d_in[11];
  const float* b_C    = (const float*)d_in[12];
  const float* W_out  = (const float*)d_in[13];
  const float* b_out  = (const float*)d_in[14];
  float* out = (float*)d_out;   // reference output dtype is float32

  char* ws = (char*)d_ws;
  size_t off = 0;
  auto alloc = [&](size_t bytes)->char* {
    char* p = ws + off; off += (bytes + 255) & ~(size_t)255; return p;
  };
  u16* Wt_in  = (u16*)alloc((size_t)(2*D_INNER)*D_MODEL*2); // 8.39 MB; dead after gemm1
  u16* Wt_out = (u16*)alloc((size_t)D_MODEL*D_INNER*2);     // 4.2 MB
  u16* xs     = (u16*)alloc((size_t)ML*D_INNER*2);          // x_ssm_silu; reused as y
  u16* gatep  = (u16*)alloc((size_t)ML*D_INNER*2);          // silu(x_res)
  u16* xconv  = (u16*)alloc((size_t)ML*D_INNER*2);
  float* Bbuf = (float*)alloc((size_t)ML*D_STATE*4);
  float* Cbuf = (float*)alloc((size_t)ML*D_STATE*4);
  u16* xbf    = (u16*)alloc((size_t)ML*D_MODEL*2);          // 16.8 MB; dead after gemm1
  float* hin  = (float*)alloc((size_t)BATCH*NCHUNK*D_INNER*16*4);
  u16* Wt_bc  = (u16*)alloc((size_t)32*D_INNER*2);          // 131 KB
  float* hend    = (float*)xbf;    // reuse: xbf dead before state_k
  float* partial = (float*)Wt_in;  // reuse: Wt_in dead after gemm1 (8.39 MB, exact)
  u16* ybuf = xs;                  // xs dead after conv/bc_gemm

  transpose_cast_k<<<dim3((2*D_INNER)/32, D_MODEL/32), 256, 0, stream>>>(W_in, Wt_in, D_MODEL, 2*D_INNER);
  transpose_cast_k<<<dim3(D_MODEL/32, D_INNER/32),     256, 0, stream>>>(W_out, Wt_out, D_INNER, D_MODEL);
  cast_k<<<dim3((ML*D_MODEL)/(256*8)), 256, 0, stream>>>(x, xbf);
  bc_wt_k<<<dim3(D_INNER/256, 32), 256, 0, stream>>>(W_B, W_C, Wt_bc);

  // gemm1: N-blocks=32 -> 4 per XCD; 2048 blocks total
  gemm_bt<1><<<dim3(2048), 256, 0, stream>>>(
      xbf, Wt_in, b_in, xs, gatep, nullptr, ML, 2*D_INNER, D_MODEL, 4);

  conv_k<<<dim3(ML), 256, 0, stream>>>(xs, conv_w, conv_b, xconv);

  bc_gemm_k<<<dim3(KSEG, ML/128), 256, 0, stream>>>(xconv, Wt_bc, partial);
  bc_reduce_k<<<dim3((ML*32)/256), 256, 0, stream>>>(
      partial, b_B, B_mod, b_C, C_mod, Bbuf, Cbuf);

  state_k<<<dim3(NCHUNK, D_INNER/256, BATCH), 256, 0, stream>>>(xconv, Bbuf, A_log, hend);
  prefix_k<<<dim3((BATCH*D_INNER*16)/256), 256, 0, stream>>>(hend, A_log, hin);
  scan2_k<<<dim3(NCHUNK, D_INNER/256, BATCH), 256, 0, stream>>>(
      xconv, gatep, Bbuf, Cbuf, A_log, Dp, hin, ybuf);

  // gemm2: N-blocks=8 -> 1 per XCD; 512 blocks total
  gemm_bt<0><<<dim3(512), 256, 0, stream>>>(
      ybuf, Wt_out, b_out, nullptr, nullptr, out, ML, D_MODEL, D_INNER, 1);
}